// Round 3
// baseline (307.216 us; speedup 1.0000x reference)
//
#include <hip/hip_runtime.h>
#include <hip/hip_bf16.h>
#include <math.h>

#define SEQ 8192
#define DIN 512
#define DH  64
#define SG  8                 // sequence splits (flash)
#define CHUNK (SEQ / SG)      // 1024 K-rows per block
#define BK  128               // K/V rows per iteration
#define NITER (CHUNK / BK)    // 8
#define LDP (BK + 8)          // padded LDS row stride (bf16): 2-way banking = free

typedef float f32x4 __attribute__((ext_vector_type(4)));
typedef short short8 __attribute__((ext_vector_type(8)));
typedef ushort us4 __attribute__((ext_vector_type(4)));

static __device__ __forceinline__ ushort bf16_of(float v) {
  __hip_bfloat16 h = __float2bfloat16(v);
  return *reinterpret_cast<ushort*>(&h);
}
static __device__ __forceinline__ float f_of_bf16(ushort u) {
  __hip_bfloat16 h;
  *reinterpret_cast<ushort*>(&h) = u;
  return __bfloat162float(h);
}
static __device__ __forceinline__ f32x4 mfma16(short8 a, short8 b, f32x4 c) {
  return __builtin_amdgcn_mfma_f32_16x16x32_bf16(a, b, c, 0, 0, 0);
}

// ---- DPP 16-lane butterfly reductions (VALU-speed, no LDS/bpermute) -------
// ctrl: 0xB1 = quad_perm(1,0,3,2)=xor1; 0x4E = quad_perm(2,3,0,1)=xor2;
// 0x141 = row_half_mirror (xor-equiv within 8); 0x140 = row_mirror (within 16).
template <int CTRL>
static __device__ __forceinline__ float dppf(float v) {
  return __int_as_float(
      __builtin_amdgcn_mov_dpp(__float_as_int(v), CTRL, 0xf, 0xf, true));
}
static __device__ __forceinline__ float red_max16(float v) {
  v = fmaxf(v, dppf<0xB1>(v));
  v = fmaxf(v, dppf<0x4E>(v));
  v = fmaxf(v, dppf<0x141>(v));
  v = fmaxf(v, dppf<0x140>(v));
  return v;
}
static __device__ __forceinline__ float red_sum16(float v) {
  v += dppf<0xB1>(v);
  v += dppf<0x4E>(v);
  v += dppf<0x141>(v);
  v += dppf<0x140>(v);
  return v;
}

// ---------------------------------------------------------------------------
// Kernel 0 (prep): transpose + hi/lo-split the three W matrices into
// Wt[mat][n][k] bf16 (contiguous in k => MFMA B-fragments are 16B loads).
// Q's 1/sqrt(64) scale folded into Wq here.  Grid 24 = 3 mats x 8 k-chunks.
// ---------------------------------------------------------------------------
__global__ __launch_bounds__(256) void prep_kernel(
    const float* __restrict__ Wq, const float* __restrict__ Wk,
    const float* __restrict__ Wv, ushort* __restrict__ Wth,
    ushort* __restrict__ Wtl) {
  __shared__ float sw[64][65];
  const int mat = blockIdx.x >> 3;
  const int kc  = blockIdx.x & 7;
  const float* W = (mat == 0) ? Wq : ((mat == 1) ? Wk : Wv);
  const float scale = (mat == 0) ? 0.125f : 1.0f;
  const int tid = threadIdx.x;
#pragma unroll
  for (int j = 0; j < 16; ++j) {
    const int i = tid + 256 * j;                    // 0..4095
    sw[i >> 6][i & 63] =
        W[(size_t)(kc * 64 + (i >> 6)) * 64 + (i & 63)] * scale;
  }
  __syncthreads();
  const int n  = tid >> 2;
  const int ks = (tid & 3) * 16;
  ushort hb[16] __attribute__((aligned(16)));
  ushort lb[16] __attribute__((aligned(16)));
#pragma unroll
  for (int j = 0; j < 16; ++j) {
    const float w = sw[ks + j][n];
    const ushort h = bf16_of(w);
    hb[j] = h;
    lb[j] = bf16_of(w - f_of_bf16(h));
  }
  const size_t base = (size_t)mat * 64 * 512 + (size_t)n * 512 + kc * 64 + ks;
  *reinterpret_cast<short8*>(Wth + base)     = *reinterpret_cast<short8*>(hb);
  *reinterpret_cast<short8*>(Wth + base + 8) = *reinterpret_cast<short8*>(hb + 8);
  *reinterpret_cast<short8*>(Wtl + base)     = *reinterpret_cast<short8*>(lb);
  *reinterpret_cast<short8*>(Wtl + base + 8) = *reinterpret_cast<short8*>(lb + 8);
}

// ---------------------------------------------------------------------------
// Kernel 1 (pgemm): projections via split-bf16 MFMA (3-pass: hh+hl+lh,
// fp32 accumulate -> near-fp32 exact).  A-frags built in-register from fp32 x.
// Grid 384 = 128 row-tiles(64 rows) x 3 mats (mat-minor for x L2 locality);
// block = 4 waves, 16 rows each.  Epilogue: hi/lo split for Q,K; V transposed.
// ---------------------------------------------------------------------------
__global__ __launch_bounds__(256) void pgemm_kernel(
    const float* __restrict__ x, const ushort* __restrict__ Wth,
    const ushort* __restrict__ Wtl,
    ushort* __restrict__ Qh, ushort* __restrict__ Ql,
    ushort* __restrict__ Kh, ushort* __restrict__ Kl,
    ushort* __restrict__ Vt) {
  const int bid = blockIdx.x;
  const int mat = bid % 3;
  const int rt  = bid / 3;
  const int tid = threadIdx.x;
  const int wv = tid >> 6, lane = tid & 63;
  const int ln = lane & 15, qd = lane >> 4;
  const int row0 = rt * 64 + wv * 16;
  const ushort* Wh = Wth + (size_t)mat * 64 * 512;
  const ushort* Wl = Wtl + (size_t)mat * 64 * 512;

  f32x4 acc[4];
#pragma unroll
  for (int nt = 0; nt < 4; ++nt)
#pragma unroll
    for (int i = 0; i < 4; ++i) acc[nt][i] = 0.f;

  for (int kt = 0; kt < 16; ++kt) {
    const float* xp = x + (size_t)(row0 + ln) * DIN + kt * 32 + qd * 8;
    float xs[8];
    *reinterpret_cast<float4*>(xs)     = *reinterpret_cast<const float4*>(xp);
    *reinterpret_cast<float4*>(xs + 4) = *reinterpret_cast<const float4*>(xp + 4);
    ushort ah[8] __attribute__((aligned(16)));
    ushort al[8] __attribute__((aligned(16)));
#pragma unroll
    for (int j = 0; j < 8; ++j) {
      const ushort h = bf16_of(xs[j]);
      ah[j] = h;
      al[j] = bf16_of(xs[j] - f_of_bf16(h));
    }
    const short8 Ah = *reinterpret_cast<short8*>(ah);
    const short8 Al = *reinterpret_cast<short8*>(al);
#pragma unroll
    for (int nt = 0; nt < 4; ++nt) {
      const size_t wo = (size_t)(nt * 16 + ln) * 512 + kt * 32 + qd * 8;
      const short8 bh = *reinterpret_cast<const short8*>(Wh + wo);
      const short8 bl = *reinterpret_cast<const short8*>(Wl + wo);
      acc[nt] = mfma16(Ah, bh, acc[nt]);
      acc[nt] = mfma16(Ah, bl, acc[nt]);
      acc[nt] = mfma16(Al, bh, acc[nt]);
    }
  }

  if (mat < 2) {
    ushort* H = (mat == 0) ? Qh : Kh;
    ushort* L = (mat == 0) ? Ql : Kl;
#pragma unroll
    for (int nt = 0; nt < 4; ++nt)
#pragma unroll
      for (int r = 0; r < 4; ++r) {
        const float v = acc[nt][r];
        const int row = row0 + qd * 4 + r;
        const int col = nt * 16 + ln;
        const ushort h = bf16_of(v);
        H[(size_t)row * DH + col] = h;
        L[(size_t)row * DH + col] = bf16_of(v - f_of_bf16(h));
      }
  } else {
#pragma unroll
    for (int nt = 0; nt < 4; ++nt) {
      ushort vp[4] __attribute__((aligned(8)));
#pragma unroll
      for (int r = 0; r < 4; ++r) vp[r] = bf16_of(acc[nt][r]);
      *reinterpret_cast<us4*>(Vt + (size_t)(nt * 16 + ln) * SEQ + row0 + qd * 4) =
          *reinterpret_cast<us4*>(vp);
    }
  }
}

// ---------------------------------------------------------------------------
// Kernel 2 (flash): barrier-free K-loop, BK=128 (8 iters), DPP softmax
// reductions, K/V B-frags straight from L2.  Grid 1024 = 128 Q-tiles x 8
// splits; block = 4 waves, 16 Q-rows each.  launch_bounds(256,3) => ~170
// VGPRs so the compiler can pipeline the 32 K-loads + 16 V-loads per iter.
// MFMA layouts (measured, m89/m120): C/D col=lane&15, row=(lane>>4)*4+reg;
// A: m=lane&15, k=(lane>>4)*8+j;  B: n=lane&15, k=(lane>>4)*8+j.
// ---------------------------------------------------------------------------
__global__ __launch_bounds__(256, 3) void flash_kernel(
    const ushort* __restrict__ Qh, const ushort* __restrict__ Ql,
    const ushort* __restrict__ Kh, const ushort* __restrict__ Kl,
    const ushort* __restrict__ Vt,
    ushort* __restrict__ Opart, float* __restrict__ Mpart,
    float* __restrict__ Lpart) {
  __shared__ __attribute__((aligned(16))) ushort sP[4][16][LDP];  // 17.4 KB

  const int tid  = threadIdx.x;
  const int wv   = tid >> 6;
  const int lane = tid & 63;
  const int ln   = lane & 15;
  const int qd   = lane >> 4;
  const int bid  = blockIdx.x;
  const int qt   = bid >> 3;
  const int sg   = bid & 7;
  const int qrow0  = qt * 64 + wv * 16;
  const int k0base = sg * CHUNK;

  short8 aqh[2], aql[2];
#pragma unroll
  for (int kt = 0; kt < 2; ++kt) {
    aqh[kt] = *reinterpret_cast<const short8*>(
        Qh + (size_t)(qrow0 + ln) * DH + kt * 32 + qd * 8);
    aql[kt] = *reinterpret_cast<const short8*>(
        Ql + (size_t)(qrow0 + ln) * DH + kt * 32 + qd * 8);
  }

  f32x4 accO[4];
  float m_r[4], l_r[4];
#pragma unroll
  for (int nt = 0; nt < 4; ++nt)
#pragma unroll
    for (int i = 0; i < 4; ++i) accO[nt][i] = 0.f;
#pragma unroll
  for (int r = 0; r < 4; ++r) { m_r[r] = -INFINITY; l_r[r] = 0.f; }

  for (int it = 0; it < NITER; ++it) {
    const int k0 = k0base + it * BK;

    // S tile (16x128): 3-pass split-precision MFMA
    f32x4 accS[8];
#pragma unroll
    for (int nt = 0; nt < 8; ++nt) {
#pragma unroll
      for (int i = 0; i < 4; ++i) accS[nt][i] = 0.f;
      const size_t ko = (size_t)(k0 + nt * 16 + ln) * DH + qd * 8;
      const short8 bh0 = *reinterpret_cast<const short8*>(Kh + ko);
      const short8 bh1 = *reinterpret_cast<const short8*>(Kh + ko + 32);
      const short8 bl0 = *reinterpret_cast<const short8*>(Kl + ko);
      const short8 bl1 = *reinterpret_cast<const short8*>(Kl + ko + 32);
      accS[nt] = mfma16(aqh[0], bh0, accS[nt]);
      accS[nt] = mfma16(aqh[1], bh1, accS[nt]);
      accS[nt] = mfma16(aqh[0], bl0, accS[nt]);
      accS[nt] = mfma16(aqh[1], bl1, accS[nt]);
      accS[nt] = mfma16(aql[0], bh0, accS[nt]);
      accS[nt] = mfma16(aql[1], bh1, accS[nt]);
    }

    // V B-fragments issued here so their latency overlaps the softmax VALU
    short8 bv[4][4];
#pragma unroll
    for (int nt2 = 0; nt2 < 4; ++nt2)
#pragma unroll
      for (int kt2 = 0; kt2 < 4; ++kt2)
        bv[nt2][kt2] = *reinterpret_cast<const short8*>(
            Vt + (size_t)(nt2 * 16 + ln) * SEQ + k0 + kt2 * 32 + qd * 8);

    // online softmax: DPP butterfly reductions across the 16-lane row group
#pragma unroll
    for (int r = 0; r < 4; ++r) {
      float mx = accS[0][r];
#pragma unroll
      for (int nt = 1; nt < 8; ++nt) mx = fmaxf(mx, accS[nt][r]);
      mx = red_max16(mx);
      const float mnew  = fmaxf(m_r[r], mx);
      const float alpha = __expf(m_r[r] - mnew);
      float ps = 0.f;
#pragma unroll
      for (int nt = 0; nt < 8; ++nt) {
        const float p = __expf(accS[nt][r] - mnew);
        sP[wv][qd * 4 + r][nt * 16 + ln] = bf16_of(p);
        ps += p;
      }
      ps = red_sum16(ps);
      l_r[r] = l_r[r] * alpha + ps;
      m_r[r] = mnew;
#pragma unroll
      for (int nt2 = 0; nt2 < 4; ++nt2) accO[nt2][r] *= alpha;
    }
    // no barrier: sP[wv] is wave-private; DS pipe is in-order per wave

    // O += P @ V
#pragma unroll
    for (int kt2 = 0; kt2 < 4; ++kt2) {
      const short8 ap =
          *reinterpret_cast<const short8*>(&sP[wv][ln][kt2 * 32 + qd * 8]);
#pragma unroll
      for (int nt2 = 0; nt2 < 4; ++nt2)
        accO[nt2] = mfma16(ap, bv[nt2][kt2], accO[nt2]);
    }
  }

  // partials: un-normalized O (bf16), running m and l (fp32)
  ushort* Ob = Opart + ((size_t)sg * SEQ + qrow0) * DH;
#pragma unroll
  for (int nt = 0; nt < 4; ++nt)
#pragma unroll
    for (int r = 0; r < 4; ++r)
      Ob[(qd * 4 + r) * DH + nt * 16 + ln] = bf16_of(accO[nt][r]);
  if (ln == 0) {
#pragma unroll
    for (int r = 0; r < 4; ++r) {
      Mpart[(size_t)sg * SEQ + qrow0 + qd * 4 + r] = m_r[r];
      Lpart[(size_t)sg * SEQ + qrow0 + qd * 4 + r] = l_r[r];
    }
  }
}

// ---------------------------------------------------------------------------
// Kernel 3: log-sum-exp merge of the 8 seq-split partials + normalize.
// ---------------------------------------------------------------------------
__global__ __launch_bounds__(256) void merge_kernel(
    const ushort* __restrict__ Opart, const float* __restrict__ Mpart,
    const float* __restrict__ Lpart, float* __restrict__ out) {
  const int idx = blockIdx.x * 256 + threadIdx.x;   // 0 .. SEQ*DH
  const int row = idx >> 6;
  const int col = idx & 63;

  float m[SG];
  float M = -INFINITY;
#pragma unroll
  for (int i = 0; i < SG; ++i) {
    m[i] = Mpart[(size_t)i * SEQ + row];
    M = fmaxf(M, m[i]);
  }
  float L = 0.f, acc = 0.f;
#pragma unroll
  for (int i = 0; i < SG; ++i) {
    const float w = __expf(m[i] - M);
    L   += w * Lpart[(size_t)i * SEQ + row];
    acc += w * f_of_bf16(Opart[((size_t)i * SEQ + row) * DH + col]);
  }
  out[idx] = acc / L;
}

// ---------------------------------------------------------------------------
extern "C" void kernel_launch(void* const* d_in, const int* in_sizes, int n_in,
                              void* d_out, int out_size, void* d_ws, size_t ws_size,
                              hipStream_t stream) {
  const float* x  = (const float*)d_in[0];
  const float* Wq = (const float*)d_in[1];
  const float* Wk = (const float*)d_in[2];
  const float* Wv = (const float*)d_in[3];
  float* out = (float*)d_out;

  // workspace layout — total 14,155,776 B, identical to round-2-proven size.
  // Wt aliases the start of Op (Wt dead before flash writes Op).
  const size_t S64 = (size_t)SEQ * DH;        // 524288
  ushort* Qh = (ushort*)d_ws;
  ushort* Ql = Qh + S64;
  ushort* Kh = Ql + S64;
  ushort* Kl = Kh + S64;
  ushort* Vt = Kl + S64;
  ushort* Op = Vt + S64;                      // [SG][SEQ][DH] bf16
  ushort* Wth = Op;                           // alias (3*64*512 = 98304 elems)
  ushort* Wtl = Wth + (size_t)3 * 64 * 512;
  float*  Mp = (float*)(Op + (size_t)SG * S64);
  float*  Lp = Mp + (size_t)SG * SEQ;

  prep_kernel<<<24, 256, 0, stream>>>(Wq, Wk, Wv, Wth, Wtl);
  pgemm_kernel<<<384, 256, 0, stream>>>(x, Wth, Wtl, Qh, Ql, Kh, Kl, Vt);
  flash_kernel<<<(SEQ / 64) * SG, 256, 0, stream>>>(Qh, Ql, Kh, Kl, Vt, Op, Mp, Lp);
  merge_kernel<<<(SEQ * DH) / 256, 256, 0, stream>>>(Op, Mp, Lp, out);
}

// Round 4
// 279.620 us; speedup vs baseline: 1.0987x; 1.0987x over previous
//
#include <hip/hip_runtime.h>
#include <hip/hip_bf16.h>
#include <math.h>

#define SEQ 8192
#define DIN 512
#define DH  64
#define SG  8                 // sequence splits (aligned to the 8 XCDs)
#define CHUNK (SEQ / SG)      // 1024 K-rows per (qtile,sg) block
#define KHALF (CHUNK / 2)     // 512 K-rows per wave
#define BK  64                // K/V rows per iteration
#define NIT (KHALF / BK)      // 8 iterations per wave
#define LDP 72                // padded LDS row stride (bf16): 2-way banking = free

typedef float f32x4 __attribute__((ext_vector_type(4)));
typedef short short8 __attribute__((ext_vector_type(8)));
typedef ushort us4 __attribute__((ext_vector_type(4)));

static __device__ __forceinline__ ushort bf16_of(float v) {
  __hip_bfloat16 h = __float2bfloat16(v);
  return *reinterpret_cast<ushort*>(&h);
}
static __device__ __forceinline__ float f_of_bf16(ushort u) {
  __hip_bfloat16 h;
  *reinterpret_cast<ushort*>(&h) = u;
  return __bfloat162float(h);
}
static __device__ __forceinline__ f32x4 mfma16(short8 a, short8 b, f32x4 c) {
  return __builtin_amdgcn_mfma_f32_16x16x32_bf16(a, b, c, 0, 0, 0);
}

// ---- DPP 16-lane butterfly reductions (VALU-speed) ------------------------
template <int CTRL>
static __device__ __forceinline__ float dppf(float v) {
  return __int_as_float(
      __builtin_amdgcn_mov_dpp(__float_as_int(v), CTRL, 0xf, 0xf, true));
}
static __device__ __forceinline__ float red_max16(float v) {
  v = fmaxf(v, dppf<0xB1>(v));    // quad_perm xor1
  v = fmaxf(v, dppf<0x4E>(v));    // quad_perm xor2
  v = fmaxf(v, dppf<0x141>(v));   // row_half_mirror
  v = fmaxf(v, dppf<0x140>(v));   // row_mirror
  return v;
}
static __device__ __forceinline__ float red_sum16(float v) {
  v += dppf<0xB1>(v);
  v += dppf<0x4E>(v);
  v += dppf<0x141>(v);
  v += dppf<0x140>(v);
  return v;
}

// ---------------------------------------------------------------------------
// Kernel 0 (prep): transpose + hi/lo-split W into Wt[mat][n][k] bf16.
// Q's 1/sqrt(64) scale folded into Wq.  Grid 24 = 3 mats x 8 k-chunks.
// ---------------------------------------------------------------------------
__global__ __launch_bounds__(256) void prep_kernel(
    const float* __restrict__ Wq, const float* __restrict__ Wk,
    const float* __restrict__ Wv, ushort* __restrict__ Wth,
    ushort* __restrict__ Wtl) {
  __shared__ float sw[64][65];
  const int mat = blockIdx.x >> 3;
  const int kc  = blockIdx.x & 7;
  const float* W = (mat == 0) ? Wq : ((mat == 1) ? Wk : Wv);
  const float scale = (mat == 0) ? 0.125f : 1.0f;
  const int tid = threadIdx.x;
#pragma unroll
  for (int j = 0; j < 16; ++j) {
    const int i = tid + 256 * j;                    // 0..4095
    sw[i >> 6][i & 63] =
        W[(size_t)(kc * 64 + (i >> 6)) * 64 + (i & 63)] * scale;
  }
  __syncthreads();
  const int n  = tid >> 2;
  const int ks = (tid & 3) * 16;
  ushort hb[16] __attribute__((aligned(16)));
  ushort lb[16] __attribute__((aligned(16)));
#pragma unroll
  for (int j = 0; j < 16; ++j) {
    const float w = sw[ks + j][n];
    const ushort h = bf16_of(w);
    hb[j] = h;
    lb[j] = bf16_of(w - f_of_bf16(h));
  }
  const size_t base = (size_t)mat * 64 * 512 + (size_t)n * 512 + kc * 64 + ks;
  *reinterpret_cast<short8*>(Wth + base)     = *reinterpret_cast<short8*>(hb);
  *reinterpret_cast<short8*>(Wth + base + 8) = *reinterpret_cast<short8*>(hb + 8);
  *reinterpret_cast<short8*>(Wtl + base)     = *reinterpret_cast<short8*>(lb);
  *reinterpret_cast<short8*>(Wtl + base + 8) = *reinterpret_cast<short8*>(lb + 8);
}

// ---------------------------------------------------------------------------
// Kernel 1 (pgemm): projections via 3-pass split-bf16 MFMA.
// Block = 32 rows, 4 waves = 2 Q-subtiles x 2 K-halves (8 kt-iters each),
// pair-merged (fp32 add) through LDS.  Grid 768 = 256 row-tiles x 3 mats.
// ---------------------------------------------------------------------------
__global__ __launch_bounds__(256, 3) void pgemm_kernel(
    const float* __restrict__ x, const ushort* __restrict__ Wth,
    const ushort* __restrict__ Wtl,
    ushort* __restrict__ Qh, ushort* __restrict__ Ql,
    ushort* __restrict__ Kh, ushort* __restrict__ Kl,
    ushort* __restrict__ Vt) {
  __shared__ float sacc[2][16][65];   // 8.3 KB, pair-merge buffer
  const int bid = blockIdx.x;
  const int mat = bid % 3;
  const int rt  = bid / 3;            // 0..255 (32-row tiles)
  const int tid = threadIdx.x;
  const int wv = tid >> 6, lane = tid & 63;
  const int ln = lane & 15, qd = lane >> 4;
  const int qsub = wv & 1, khalf = wv >> 1;
  const int row0 = rt * 32 + qsub * 16;
  const ushort* Wh = Wth + (size_t)mat * 64 * 512;
  const ushort* Wl = Wtl + (size_t)mat * 64 * 512;

  f32x4 acc[4];
#pragma unroll
  for (int nt = 0; nt < 4; ++nt)
#pragma unroll
    for (int i = 0; i < 4; ++i) acc[nt][i] = 0.f;

  for (int kt = 0; kt < 8; ++kt) {
    const int ktg = khalf * 8 + kt;
    const float* xp = x + (size_t)(row0 + ln) * DIN + ktg * 32 + qd * 8;
    float xs[8];
    *reinterpret_cast<float4*>(xs)     = *reinterpret_cast<const float4*>(xp);
    *reinterpret_cast<float4*>(xs + 4) = *reinterpret_cast<const float4*>(xp + 4);
    ushort ah[8] __attribute__((aligned(16)));
    ushort al[8] __attribute__((aligned(16)));
#pragma unroll
    for (int j = 0; j < 8; ++j) {
      const ushort h = bf16_of(xs[j]);
      ah[j] = h;
      al[j] = bf16_of(xs[j] - f_of_bf16(h));
    }
    const short8 Ah = *reinterpret_cast<short8*>(ah);
    const short8 Al = *reinterpret_cast<short8*>(al);
#pragma unroll
    for (int nt = 0; nt < 4; ++nt) {
      const size_t wo = (size_t)(nt * 16 + ln) * 512 + ktg * 32 + qd * 8;
      const short8 bh = *reinterpret_cast<const short8*>(Wh + wo);
      const short8 bl = *reinterpret_cast<const short8*>(Wl + wo);
      acc[nt] = mfma16(Ah, bh, acc[nt]);
      acc[nt] = mfma16(Ah, bl, acc[nt]);
      acc[nt] = mfma16(Al, bh, acc[nt]);
    }
  }

  __syncthreads();
  if (khalf == 1) {
#pragma unroll
    for (int nt = 0; nt < 4; ++nt)
#pragma unroll
      for (int r = 0; r < 4; ++r)
        sacc[qsub][qd * 4 + r][nt * 16 + ln] = acc[nt][r];
  }
  __syncthreads();
  if (khalf == 0) {
#pragma unroll
    for (int nt = 0; nt < 4; ++nt)
#pragma unroll
      for (int r = 0; r < 4; ++r)
        acc[nt][r] += sacc[qsub][qd * 4 + r][nt * 16 + ln];

    if (mat < 2) {
      ushort* H = (mat == 0) ? Qh : Kh;
      ushort* L = (mat == 0) ? Ql : Kl;
#pragma unroll
      for (int nt = 0; nt < 4; ++nt)
#pragma unroll
        for (int r = 0; r < 4; ++r) {
          const float v = acc[nt][r];
          const int row = row0 + qd * 4 + r;
          const int col = nt * 16 + ln;
          const ushort h = bf16_of(v);
          H[(size_t)row * DH + col] = h;
          L[(size_t)row * DH + col] = bf16_of(v - f_of_bf16(h));
        }
    } else {
#pragma unroll
      for (int nt = 0; nt < 4; ++nt) {
        ushort vp[4] __attribute__((aligned(8)));
#pragma unroll
        for (int r = 0; r < 4; ++r) vp[r] = bf16_of(acc[nt][r]);
        *reinterpret_cast<us4*>(Vt + (size_t)(nt * 16 + ln) * SEQ + row0 + qd * 4) =
            *reinterpret_cast<us4*>(vp);
      }
    }
  }
}

// ---------------------------------------------------------------------------
// Kernel 2 (flash): barrier-free K-loop, XCD-aligned seq-splits.
// sg = bid & 7 -> round-robin dispatch puts each seq-chunk on its own XCD,
// so that chunk's K/V (~0.65 MB) is L2-resident (load latency ~220 not ~900).
// Block = 32 Q-rows, 4 waves = 2 Q-subtiles x 2 K-halves (8 iters each);
// halves pair-merged (log-sum-exp) through LDS at block end.
// MFMA layouts (measured, m89/m120): C/D col=lane&15, row=(lane>>4)*4+reg;
// A: m=lane&15, k=(lane>>4)*8+j;  B: n=lane&15, k=(lane>>4)*8+j.
// launch_bounds(256,5): VGPR cap ~102 (R2 body used 60 arch + 32 acc) -> no
// spills (R3's 31 MB WRITE_SIZE lesson), ~5 blocks/CU resident.
// ---------------------------------------------------------------------------
__global__ __launch_bounds__(256, 5) void flash_kernel(
    const ushort* __restrict__ Qh, const ushort* __restrict__ Ql,
    const ushort* __restrict__ Kh, const ushort* __restrict__ Kl,
    const ushort* __restrict__ Vt,
    ushort* __restrict__ Opart, float* __restrict__ Mpart,
    float* __restrict__ Lpart) {
  __shared__ __attribute__((aligned(16))) ushort sP[4][16][LDP];  // 9.2 KB
  __shared__ float sO[2][16][65];                                  // 8.3 KB
  __shared__ float sML[2][2][16];

  const int tid  = threadIdx.x;
  const int wv   = tid >> 6;
  const int lane = tid & 63;
  const int ln   = lane & 15;
  const int qd   = lane >> 4;
  const int bid  = blockIdx.x;
  const int sg   = bid & 7;         // == XCD id under round-robin dispatch
  const int qt   = bid >> 3;        // 0..255 (32-row Q tiles)
  const int qsub = wv & 1, khalf = wv >> 1;
  const int qrow0  = qt * 32 + qsub * 16;
  const int k0base = sg * CHUNK + khalf * KHALF;

  short8 aqh[2], aql[2];
#pragma unroll
  for (int kt = 0; kt < 2; ++kt) {
    aqh[kt] = *reinterpret_cast<const short8*>(
        Qh + (size_t)(qrow0 + ln) * DH + kt * 32 + qd * 8);
    aql[kt] = *reinterpret_cast<const short8*>(
        Ql + (size_t)(qrow0 + ln) * DH + kt * 32 + qd * 8);
  }

  f32x4 accO[4];
  float m_r[4], l_r[4];
#pragma unroll
  for (int nt = 0; nt < 4; ++nt)
#pragma unroll
    for (int i = 0; i < 4; ++i) accO[nt][i] = 0.f;
#pragma unroll
  for (int r = 0; r < 4; ++r) { m_r[r] = -INFINITY; l_r[r] = 0.f; }

  for (int it = 0; it < NIT; ++it) {
    const int k0 = k0base + it * BK;

    // S tile (16x64): 3-pass split-precision MFMA, B-frags from XCD-local L2
    f32x4 accS[4];
#pragma unroll
    for (int nt = 0; nt < 4; ++nt) {
#pragma unroll
      for (int i = 0; i < 4; ++i) accS[nt][i] = 0.f;
      const size_t ko = (size_t)(k0 + nt * 16 + ln) * DH + qd * 8;
      const short8 bh0 = *reinterpret_cast<const short8*>(Kh + ko);
      const short8 bh1 = *reinterpret_cast<const short8*>(Kh + ko + 32);
      const short8 bl0 = *reinterpret_cast<const short8*>(Kl + ko);
      const short8 bl1 = *reinterpret_cast<const short8*>(Kl + ko + 32);
      accS[nt] = mfma16(aqh[0], bh0, accS[nt]);
      accS[nt] = mfma16(aqh[1], bh1, accS[nt]);
      accS[nt] = mfma16(aqh[0], bl0, accS[nt]);
      accS[nt] = mfma16(aqh[1], bl1, accS[nt]);
      accS[nt] = mfma16(aql[0], bh0, accS[nt]);
      accS[nt] = mfma16(aql[1], bh1, accS[nt]);
    }

    // online softmax: DPP butterfly across the 16-lane row group
#pragma unroll
    for (int r = 0; r < 4; ++r) {
      float mx = fmaxf(fmaxf(accS[0][r], accS[1][r]),
                       fmaxf(accS[2][r], accS[3][r]));
      mx = red_max16(mx);
      const float mnew  = fmaxf(m_r[r], mx);
      const float alpha = __expf(m_r[r] - mnew);
      float ps = 0.f;
#pragma unroll
      for (int nt = 0; nt < 4; ++nt) {
        const float p = __expf(accS[nt][r] - mnew);
        sP[wv][qd * 4 + r][nt * 16 + ln] = bf16_of(p);
        ps += p;
      }
      ps = red_sum16(ps);
      l_r[r] = l_r[r] * alpha + ps;
      m_r[r] = mnew;
#pragma unroll
      for (int nt = 0; nt < 4; ++nt) accO[nt][r] *= alpha;
    }
    // no barrier: sP[wv] is wave-private; DS pipe is in-order per wave

    // O += P @ V
#pragma unroll
    for (int kt2 = 0; kt2 < 2; ++kt2) {
      const short8 ap =
          *reinterpret_cast<const short8*>(&sP[wv][ln][kt2 * 32 + qd * 8]);
#pragma unroll
      for (int nt2 = 0; nt2 < 4; ++nt2) {
        const short8 bv = *reinterpret_cast<const short8*>(
            Vt + (size_t)(nt2 * 16 + ln) * SEQ + k0 + kt2 * 32 + qd * 8);
        accO[nt2] = mfma16(ap, bv, accO[nt2]);
      }
    }
  }

  // ---- pair-merge the two K-halves (log-sum-exp) through LDS --------------
  __syncthreads();
  if (khalf == 1) {
#pragma unroll
    for (int nt = 0; nt < 4; ++nt)
#pragma unroll
      for (int r = 0; r < 4; ++r)
        sO[qsub][qd * 4 + r][nt * 16 + ln] = accO[nt][r];
    if (ln == 0) {
#pragma unroll
      for (int r = 0; r < 4; ++r) {
        sML[qsub][0][qd * 4 + r] = m_r[r];
        sML[qsub][1][qd * 4 + r] = l_r[r];
      }
    }
  }
  __syncthreads();
  if (khalf == 0) {
    ushort* Ob = Opart + ((size_t)sg * SEQ + qrow0) * DH;
#pragma unroll
    for (int r = 0; r < 4; ++r) {
      const float m2 = sML[qsub][0][qd * 4 + r];
      const float l2 = sML[qsub][1][qd * 4 + r];
      const float M  = fmaxf(m_r[r], m2);
      const float a1 = __expf(m_r[r] - M);
      const float a2 = __expf(m2 - M);
#pragma unroll
      for (int nt = 0; nt < 4; ++nt) {
        const float o =
            accO[nt][r] * a1 + sO[qsub][qd * 4 + r][nt * 16 + ln] * a2;
        Ob[(qd * 4 + r) * DH + nt * 16 + ln] = bf16_of(o);
      }
      if (ln == 0) {
        Mpart[(size_t)sg * SEQ + qrow0 + qd * 4 + r] = M;
        Lpart[(size_t)sg * SEQ + qrow0 + qd * 4 + r] = l_r[r] * a1 + l2 * a2;
      }
    }
  }
}

// ---------------------------------------------------------------------------
// Kernel 3: log-sum-exp merge of the 8 seq-split partials + normalize.
// ---------------------------------------------------------------------------
__global__ __launch_bounds__(256) void merge_kernel(
    const ushort* __restrict__ Opart, const float* __restrict__ Mpart,
    const float* __restrict__ Lpart, float* __restrict__ out) {
  const int idx = blockIdx.x * 256 + threadIdx.x;   // 0 .. SEQ*DH
  const int row = idx >> 6;
  const int col = idx & 63;

  float m[SG];
  float M = -INFINITY;
#pragma unroll
  for (int i = 0; i < SG; ++i) {
    m[i] = Mpart[(size_t)i * SEQ + row];
    M = fmaxf(M, m[i]);
  }
  float L = 0.f, acc = 0.f;
#pragma unroll
  for (int i = 0; i < SG; ++i) {
    const float w = __expf(m[i] - M);
    L   += w * Lpart[(size_t)i * SEQ + row];
    acc += w * f_of_bf16(Opart[((size_t)i * SEQ + row) * DH + col]);
  }
  out[idx] = acc / L;
}

// ---------------------------------------------------------------------------
extern "C" void kernel_launch(void* const* d_in, const int* in_sizes, int n_in,
                              void* d_out, int out_size, void* d_ws, size_t ws_size,
                              hipStream_t stream) {
  const float* x  = (const float*)d_in[0];
  const float* Wq = (const float*)d_in[1];
  const float* Wk = (const float*)d_in[2];
  const float* Wv = (const float*)d_in[3];
  float* out = (float*)d_out;

  // workspace layout — total 14,155,776 B (round-2/3-proven size).
  // Wt aliases the start of Op (Wt dead before flash writes Op).
  const size_t S64 = (size_t)SEQ * DH;        // 524288
  ushort* Qh = (ushort*)d_ws;
  ushort* Ql = Qh + S64;
  ushort* Kh = Ql + S64;
  ushort* Kl = Kh + S64;
  ushort* Vt = Kl + S64;
  ushort* Op = Vt + S64;                      // [SG][SEQ][DH] bf16
  ushort* Wth = Op;                           // alias (3*64*512 elems)
  ushort* Wtl = Wth + (size_t)3 * 64 * 512;
  float*  Mp = (float*)(Op + (size_t)SG * S64);
  float*  Lp = Mp + (size_t)SG * SEQ;

  prep_kernel<<<24, 256, 0, stream>>>(Wq, Wk, Wv, Wth, Wtl);
  pgemm_kernel<<<768, 256, 0, stream>>>(x, Wth, Wtl, Qh, Ql, Kh, Kl, Vt);
  flash_kernel<<<(SEQ / 32) * SG, 256, 0, stream>>>(Qh, Ql, Kh, Kl, Vt, Op, Mp, Lp);
  merge_kernel<<<(SEQ * DH) / 256, 256, 0, stream>>>(Op, Mp, Lp, out);
}

// Round 5
// 159.698 us; speedup vs baseline: 1.9237x; 1.7509x over previous
//
#include <hip/hip_runtime.h>
#include <hip/hip_bf16.h>
#include <math.h>

#define SEQ 8192
#define DIN 512
#define DH  64
#define SG  8                 // sequence splits
#define CHUNK (SEQ / SG)      // 1024 K-rows per block
#define BK  64                // K/V rows per iteration
#define NIT (CHUNK / BK)      // 16 iterations
#define LDP 72                // padded LDS row stride (bf16); 144B = 16B-aligned

typedef float f32x4 __attribute__((ext_vector_type(4)));
typedef short short8 __attribute__((ext_vector_type(8)));
typedef ushort us4 __attribute__((ext_vector_type(4)));

static __device__ __forceinline__ ushort bf16_of(float v) {
  __hip_bfloat16 h = __float2bfloat16(v);
  return *reinterpret_cast<ushort*>(&h);
}
static __device__ __forceinline__ float f_of_bf16(ushort u) {
  __hip_bfloat16 h;
  *reinterpret_cast<ushort*>(&h) = u;
  return __bfloat162float(h);
}
static __device__ __forceinline__ f32x4 mfma16(short8 a, short8 b, f32x4 c) {
  return __builtin_amdgcn_mfma_f32_16x16x32_bf16(a, b, c, 0, 0, 0);
}

// ---- DPP 16-lane butterfly reductions (VALU-speed) ------------------------
template <int CTRL>
static __device__ __forceinline__ float dppf(float v) {
  return __int_as_float(
      __builtin_amdgcn_mov_dpp(__float_as_int(v), CTRL, 0xf, 0xf, true));
}
static __device__ __forceinline__ float red_max16(float v) {
  v = fmaxf(v, dppf<0xB1>(v));    // quad_perm xor1
  v = fmaxf(v, dppf<0x4E>(v));    // quad_perm xor2
  v = fmaxf(v, dppf<0x141>(v));   // row_half_mirror
  v = fmaxf(v, dppf<0x140>(v));   // row_mirror
  return v;
}
static __device__ __forceinline__ float red_sum16(float v) {
  v += dppf<0xB1>(v);
  v += dppf<0x4E>(v);
  v += dppf<0x141>(v);
  v += dppf<0x140>(v);
  return v;
}

// ---------------------------------------------------------------------------
// Kernel 0 (prep): transpose + hi/lo-split W into Wt[mat][n][k] bf16.
// Q gets 0.125 * log2(e) folded in -> all softmax exponentials become bare
// v_exp_f32 (exp2 domain end-to-end, incl. merge).
// ---------------------------------------------------------------------------
__global__ __launch_bounds__(256) void prep_kernel(
    const float* __restrict__ Wq, const float* __restrict__ Wk,
    const float* __restrict__ Wv, ushort* __restrict__ Wth,
    ushort* __restrict__ Wtl) {
  __shared__ float sw[64][65];
  const int mat = blockIdx.x >> 3;
  const int kc  = blockIdx.x & 7;
  const float* W = (mat == 0) ? Wq : ((mat == 1) ? Wk : Wv);
  const float scale = (mat == 0) ? 0.125f * 1.44269504088896f : 1.0f;
  const int tid = threadIdx.x;
#pragma unroll
  for (int j = 0; j < 16; ++j) {
    const int i = tid + 256 * j;                    // 0..4095
    sw[i >> 6][i & 63] =
        W[(size_t)(kc * 64 + (i >> 6)) * 64 + (i & 63)] * scale;
  }
  __syncthreads();
  const int n  = tid >> 2;
  const int ks = (tid & 3) * 16;
  ushort hb[16] __attribute__((aligned(16)));
  ushort lb[16] __attribute__((aligned(16)));
#pragma unroll
  for (int j = 0; j < 16; ++j) {
    const float w = sw[ks + j][n];
    const ushort h = bf16_of(w);
    hb[j] = h;
    lb[j] = bf16_of(w - f_of_bf16(h));
  }
  const size_t base = (size_t)mat * 64 * 512 + (size_t)n * 512 + kc * 64 + ks;
  *reinterpret_cast<short8*>(Wth + base)     = *reinterpret_cast<short8*>(hb);
  *reinterpret_cast<short8*>(Wth + base + 8) = *reinterpret_cast<short8*>(hb + 8);
  *reinterpret_cast<short8*>(Wtl + base)     = *reinterpret_cast<short8*>(lb);
  *reinterpret_cast<short8*>(Wtl + base + 8) = *reinterpret_cast<short8*>(lb + 8);
}

// ---------------------------------------------------------------------------
// Kernel 1 (pgemm): projections via 3-pass split-bf16 MFMA (unchanged R4).
// ---------------------------------------------------------------------------
__global__ __launch_bounds__(256, 3) void pgemm_kernel(
    const float* __restrict__ x, const ushort* __restrict__ Wth,
    const ushort* __restrict__ Wtl,
    ushort* __restrict__ Qh, ushort* __restrict__ Ql,
    ushort* __restrict__ Kh, ushort* __restrict__ Kl,
    ushort* __restrict__ Vt) {
  __shared__ float sacc[2][16][65];
  const int bid = blockIdx.x;
  const int mat = bid % 3;
  const int rt  = bid / 3;
  const int tid = threadIdx.x;
  const int wv = tid >> 6, lane = tid & 63;
  const int ln = lane & 15, qd = lane >> 4;
  const int qsub = wv & 1, khalf = wv >> 1;
  const int row0 = rt * 32 + qsub * 16;
  const ushort* Wh = Wth + (size_t)mat * 64 * 512;
  const ushort* Wl = Wtl + (size_t)mat * 64 * 512;

  f32x4 acc[4];
#pragma unroll
  for (int nt = 0; nt < 4; ++nt)
#pragma unroll
    for (int i = 0; i < 4; ++i) acc[nt][i] = 0.f;

  for (int kt = 0; kt < 8; ++kt) {
    const int ktg = khalf * 8 + kt;
    const float* xp = x + (size_t)(row0 + ln) * DIN + ktg * 32 + qd * 8;
    float xs[8];
    *reinterpret_cast<float4*>(xs)     = *reinterpret_cast<const float4*>(xp);
    *reinterpret_cast<float4*>(xs + 4) = *reinterpret_cast<const float4*>(xp + 4);
    ushort ah[8] __attribute__((aligned(16)));
    ushort al[8] __attribute__((aligned(16)));
#pragma unroll
    for (int j = 0; j < 8; ++j) {
      const ushort h = bf16_of(xs[j]);
      ah[j] = h;
      al[j] = bf16_of(xs[j] - f_of_bf16(h));
    }
    const short8 Ah = *reinterpret_cast<short8*>(ah);
    const short8 Al = *reinterpret_cast<short8*>(al);
#pragma unroll
    for (int nt = 0; nt < 4; ++nt) {
      const size_t wo = (size_t)(nt * 16 + ln) * 512 + ktg * 32 + qd * 8;
      const short8 bh = *reinterpret_cast<const short8*>(Wh + wo);
      const short8 bl = *reinterpret_cast<const short8*>(Wl + wo);
      acc[nt] = mfma16(Ah, bh, acc[nt]);
      acc[nt] = mfma16(Ah, bl, acc[nt]);
      acc[nt] = mfma16(Al, bh, acc[nt]);
    }
  }

  __syncthreads();
  if (khalf == 1) {
#pragma unroll
    for (int nt = 0; nt < 4; ++nt)
#pragma unroll
      for (int r = 0; r < 4; ++r)
        sacc[qsub][qd * 4 + r][nt * 16 + ln] = acc[nt][r];
  }
  __syncthreads();
  if (khalf == 0) {
#pragma unroll
    for (int nt = 0; nt < 4; ++nt)
#pragma unroll
      for (int r = 0; r < 4; ++r)
        acc[nt][r] += sacc[qsub][qd * 4 + r][nt * 16 + ln];

    if (mat < 2) {
      ushort* H = (mat == 0) ? Qh : Kh;
      ushort* L = (mat == 0) ? Ql : Kl;
#pragma unroll
      for (int nt = 0; nt < 4; ++nt)
#pragma unroll
        for (int r = 0; r < 4; ++r) {
          const float v = acc[nt][r];
          const int row = row0 + qd * 4 + r;
          const int col = nt * 16 + ln;
          const ushort h = bf16_of(v);
          H[(size_t)row * DH + col] = h;
          L[(size_t)row * DH + col] = bf16_of(v - f_of_bf16(h));
        }
    } else {
#pragma unroll
      for (int nt = 0; nt < 4; ++nt) {
        ushort vp[4] __attribute__((aligned(8)));
#pragma unroll
        for (int r = 0; r < 4; ++r) vp[r] = bf16_of(acc[nt][r]);
        *reinterpret_cast<us4*>(Vt + (size_t)(nt * 16 + ln) * SEQ + row0 + qd * 4) =
            *reinterpret_cast<us4*>(vp);
      }
    }
  }
}

// ---------------------------------------------------------------------------
// Kernel 2 (flash): LDS-staged K/V with REGISTER PREFETCH decoupling.
// R1-R4 lesson: global-direct B-frags stall ~1k cyc per JIT load batch
// (working set > per-XCD L2).  Here: next tile's 6 uint4 loads are issued
// BEFORE the current tile's compute, so global latency hides under a full
// compute phase; tiles land in (block-shared) LDS; all 4 waves reuse them.
// Block = 64 Q-rows (4 waves x 16); grid = 128 qtiles x 8 sg = 1024 ->
// 4 blocks/CU (LDS 36 KB), 16 waves/CU.  Exp2 domain softmax (log2e folded
// into Q by prep) -> bare v_exp_f32.
// MFMA layouts (measured, m89/m120): C/D col=lane&15, row=(lane>>4)*4+reg;
// A: m=lane&15, k=(lane>>4)*8+j;  B: n=lane&15, k=(lane>>4)*8+j.
// ---------------------------------------------------------------------------
__global__ __launch_bounds__(256, 4) void flash_kernel(
    const ushort* __restrict__ Qh, const ushort* __restrict__ Ql,
    const ushort* __restrict__ Kh, const ushort* __restrict__ Kl,
    const ushort* __restrict__ Vt,
    ushort* __restrict__ Opart, float* __restrict__ Mpart,
    float* __restrict__ Lpart) {
  __shared__ __attribute__((aligned(16))) ushort sKh[BK][LDP];   // 9.2 KB
  __shared__ __attribute__((aligned(16))) ushort sKl[BK][LDP];   // 9.2 KB
  __shared__ __attribute__((aligned(16))) ushort sVt[DH][LDP];   // [vcol][krow]
  __shared__ __attribute__((aligned(16))) ushort sP[4][16][LDP]; // 9.2 KB

  const int tid  = threadIdx.x;
  const int wv   = tid >> 6;
  const int lane = tid & 63;
  const int ln   = lane & 15;
  const int qd   = lane >> 4;
  const int bid  = blockIdx.x;
  const int sg   = bid & 7;
  const int qt   = bid >> 3;        // 0..127 (64-row Q tiles)
  const int qrow0  = qt * 64 + wv * 16;
  const int k0base = sg * CHUNK;

  // staging slices: 512 16B-chunks per tile / 256 threads = 2 each
  const int r0 = tid >> 3,           g0 = (tid & 7) * 8;
  const int r1 = (tid + 256) >> 3,   g1 = (tid & 7) * 8;  // rows 32..63

  // Q fragments (A-layout), loaded once
  short8 aqh[2], aql[2];
#pragma unroll
  for (int kt = 0; kt < 2; ++kt) {
    aqh[kt] = *reinterpret_cast<const short8*>(
        Qh + (size_t)(qrow0 + ln) * DH + kt * 32 + qd * 8);
    aql[kt] = *reinterpret_cast<const short8*>(
        Ql + (size_t)(qrow0 + ln) * DH + kt * 32 + qd * 8);
  }

  f32x4 accO[4];
  float m_r[4], l_r[4];
#pragma unroll
  for (int nt = 0; nt < 4; ++nt)
#pragma unroll
    for (int i = 0; i < 4; ++i) accO[nt][i] = 0.f;
#pragma unroll
  for (int r = 0; r < 4; ++r) { m_r[r] = -INFINITY; l_r[r] = 0.f; }

  // prefetch registers for one tile-triple
  uint4 pk0, pk1, pl0, pl1, pv0, pv1;
#define LOAD_TILES(k0_)                                                        \
  do {                                                                         \
    pk0 = *reinterpret_cast<const uint4*>(Kh + (size_t)((k0_) + r0) * DH + g0);\
    pk1 = *reinterpret_cast<const uint4*>(Kh + (size_t)((k0_) + r1) * DH + g1);\
    pl0 = *reinterpret_cast<const uint4*>(Kl + (size_t)((k0_) + r0) * DH + g0);\
    pl1 = *reinterpret_cast<const uint4*>(Kl + (size_t)((k0_) + r1) * DH + g1);\
    pv0 = *reinterpret_cast<const uint4*>(Vt + (size_t)r0 * SEQ + (k0_) + g0); \
    pv1 = *reinterpret_cast<const uint4*>(Vt + (size_t)r1 * SEQ + (k0_) + g1); \
  } while (0)

  LOAD_TILES(k0base);

  for (int it = 0; it < NIT; ++it) {
    // drain prefetched tile into LDS (vmcnt wait happens here, one phase old)
    *reinterpret_cast<uint4*>(&sKh[r0][g0]) = pk0;
    *reinterpret_cast<uint4*>(&sKh[r1][g1]) = pk1;
    *reinterpret_cast<uint4*>(&sKl[r0][g0]) = pl0;
    *reinterpret_cast<uint4*>(&sKl[r1][g1]) = pl1;
    *reinterpret_cast<uint4*>(&sVt[r0][g0]) = pv0;
    *reinterpret_cast<uint4*>(&sVt[r1][g1]) = pv1;
    __syncthreads();

    // issue next tile's loads NOW — latency hides under this iter's compute
    const int k0n = k0base + ((it + 1 < NIT) ? (it + 1) : (NIT - 1)) * BK;
    LOAD_TILES(k0n);

    // S tile (16x64): 3-pass split-precision MFMA from LDS
    f32x4 accS[4];
#pragma unroll
    for (int nt = 0; nt < 4; ++nt) {
#pragma unroll
      for (int i = 0; i < 4; ++i) accS[nt][i] = 0.f;
      const short8 bh0 = *reinterpret_cast<const short8*>(&sKh[nt * 16 + ln][qd * 8]);
      const short8 bh1 = *reinterpret_cast<const short8*>(&sKh[nt * 16 + ln][32 + qd * 8]);
      const short8 bl0 = *reinterpret_cast<const short8*>(&sKl[nt * 16 + ln][qd * 8]);
      const short8 bl1 = *reinterpret_cast<const short8*>(&sKl[nt * 16 + ln][32 + qd * 8]);
      accS[nt] = mfma16(aqh[0], bh0, accS[nt]);
      accS[nt] = mfma16(aqh[1], bh1, accS[nt]);
      accS[nt] = mfma16(aqh[0], bl0, accS[nt]);
      accS[nt] = mfma16(aqh[1], bl1, accS[nt]);
      accS[nt] = mfma16(aql[0], bh0, accS[nt]);
      accS[nt] = mfma16(aql[1], bh1, accS[nt]);
    }

    // online softmax in exp2 domain (scores already scaled by log2e)
#pragma unroll
    for (int r = 0; r < 4; ++r) {
      float mx = fmaxf(fmaxf(accS[0][r], accS[1][r]),
                       fmaxf(accS[2][r], accS[3][r]));
      mx = red_max16(mx);
      const float mnew  = fmaxf(m_r[r], mx);
      const float alpha = exp2f(m_r[r] - mnew);
      float ps = 0.f;
#pragma unroll
      for (int nt = 0; nt < 4; ++nt) {
        const float p = exp2f(accS[nt][r] - mnew);
        sP[wv][qd * 4 + r][nt * 16 + ln] = bf16_of(p);
        ps += p;
      }
      ps = red_sum16(ps);
      l_r[r] = l_r[r] * alpha + ps;
      m_r[r] = mnew;
#pragma unroll
      for (int nt = 0; nt < 4; ++nt) accO[nt][r] *= alpha;
    }
    // sP is wave-private; DS pipe in-order per wave -> no barrier needed here

    // O += P @ V
#pragma unroll
    for (int kt2 = 0; kt2 < 2; ++kt2) {
      const short8 ap =
          *reinterpret_cast<const short8*>(&sP[wv][ln][kt2 * 32 + qd * 8]);
#pragma unroll
      for (int nt2 = 0; nt2 < 4; ++nt2) {
        const short8 bv = *reinterpret_cast<const short8*>(
            &sVt[nt2 * 16 + ln][kt2 * 32 + qd * 8]);
        accO[nt2] = mfma16(ap, bv, accO[nt2]);
      }
    }
    __syncthreads();  // all waves done reading this tile before next overwrite
  }
#undef LOAD_TILES

  // partials: un-normalized O (bf16), running m and l (exp2 domain)
  ushort* Ob = Opart + ((size_t)sg * SEQ + qrow0) * DH;
#pragma unroll
  for (int nt = 0; nt < 4; ++nt)
#pragma unroll
    for (int r = 0; r < 4; ++r)
      Ob[(qd * 4 + r) * DH + nt * 16 + ln] = bf16_of(accO[nt][r]);
  if (ln == 0) {
#pragma unroll
    for (int r = 0; r < 4; ++r) {
      Mpart[(size_t)sg * SEQ + qrow0 + qd * 4 + r] = m_r[r];
      Lpart[(size_t)sg * SEQ + qrow0 + qd * 4 + r] = l_r[r];
    }
  }
}

// ---------------------------------------------------------------------------
// Kernel 3: merge of the 8 seq-split partials (exp2 domain) + normalize.
// ---------------------------------------------------------------------------
__global__ __launch_bounds__(256) void merge_kernel(
    const ushort* __restrict__ Opart, const float* __restrict__ Mpart,
    const float* __restrict__ Lpart, float* __restrict__ out) {
  const int idx = blockIdx.x * 256 + threadIdx.x;   // 0 .. SEQ*DH
  const int row = idx >> 6;
  const int col = idx & 63;

  float m[SG];
  float M = -INFINITY;
#pragma unroll
  for (int i = 0; i < SG; ++i) {
    m[i] = Mpart[(size_t)i * SEQ + row];
    M = fmaxf(M, m[i]);
  }
  float L = 0.f, acc = 0.f;
#pragma unroll
  for (int i = 0; i < SG; ++i) {
    const float w = exp2f(m[i] - M);
    L   += w * Lpart[(size_t)i * SEQ + row];
    acc += w * f_of_bf16(Opart[((size_t)i * SEQ + row) * DH + col]);
  }
  out[idx] = acc / L;
}

// ---------------------------------------------------------------------------
extern "C" void kernel_launch(void* const* d_in, const int* in_sizes, int n_in,
                              void* d_out, int out_size, void* d_ws, size_t ws_size,
                              hipStream_t stream) {
  const float* x  = (const float*)d_in[0];
  const float* Wq = (const float*)d_in[1];
  const float* Wk = (const float*)d_in[2];
  const float* Wv = (const float*)d_in[3];
  float* out = (float*)d_out;

  // workspace layout — total 14,155,776 B (round-2/3/4-proven size).
  const size_t S64 = (size_t)SEQ * DH;        // 524288
  ushort* Qh = (ushort*)d_ws;
  ushort* Ql = Qh + S64;
  ushort* Kh = Ql + S64;
  ushort* Kl = Kh + S64;
  ushort* Vt = Kl + S64;
  ushort* Op = Vt + S64;                      // [SG][SEQ][DH] bf16
  ushort* Wth = Op;                           // alias (3*64*512 elems)
  ushort* Wtl = Wth + (size_t)3 * 64 * 512;
  float*  Mp = (float*)(Op + (size_t)SG * S64);
  float*  Lp = Mp + (size_t)SG * SEQ;

  prep_kernel<<<24, 256, 0, stream>>>(Wq, Wk, Wv, Wth, Wtl);
  pgemm_kernel<<<768, 256, 0, stream>>>(x, Wth, Wtl, Qh, Ql, Kh, Kl, Vt);
  flash_kernel<<<(SEQ / 64) * SG, 256, 0, stream>>>(Qh, Ql, Kh, Kl, Vt, Op, Mp, Lp);
  merge_kernel<<<(SEQ * DH) / 256, 256, 0, stream>>>(Op, Mp, Lp, out);
}

// Round 6
// 156.439 us; speedup vs baseline: 1.9638x; 1.0208x over previous
//
#include <hip/hip_runtime.h>
#include <hip/hip_bf16.h>
#include <math.h>

#define SEQ 8192
#define DIN 512
#define DH  64
#define SG  8                 // sequence splits
#define CHUNK (SEQ / SG)      // 1024 K-rows per block
#define BK  64                // K/V rows per iteration
#define NIT (CHUNK / BK)      // 16 iterations
#define LDP 72                // padded LDS row stride (bf16); 2-way banking = free
#define SXP 516               // padded fp32 x row stride (pad 4 -> 2-way, 16B-aligned)

typedef float f32x4 __attribute__((ext_vector_type(4)));
typedef short short8 __attribute__((ext_vector_type(8)));
typedef ushort us4 __attribute__((ext_vector_type(4)));

static __device__ __forceinline__ ushort bf16_of(float v) {
  __hip_bfloat16 h = __float2bfloat16(v);
  return *reinterpret_cast<ushort*>(&h);
}
static __device__ __forceinline__ float f_of_bf16(ushort u) {
  __hip_bfloat16 h;
  *reinterpret_cast<ushort*>(&h) = u;
  return __bfloat162float(h);
}
static __device__ __forceinline__ f32x4 mfma16(short8 a, short8 b, f32x4 c) {
  return __builtin_amdgcn_mfma_f32_16x16x32_bf16(a, b, c, 0, 0, 0);
}

// ---- DPP 16-lane butterfly max (VALU-speed) -------------------------------
template <int CTRL>
static __device__ __forceinline__ float dppf(float v) {
  return __int_as_float(
      __builtin_amdgcn_mov_dpp(__float_as_int(v), CTRL, 0xf, 0xf, true));
}
static __device__ __forceinline__ float red_max16(float v) {
  v = fmaxf(v, dppf<0xB1>(v));    // quad_perm xor1
  v = fmaxf(v, dppf<0x4E>(v));    // quad_perm xor2
  v = fmaxf(v, dppf<0x141>(v));   // row_half_mirror
  v = fmaxf(v, dppf<0x140>(v));   // row_mirror
  return v;
}

// ---------------------------------------------------------------------------
// Kernel 0 (prep): transpose + hi/lo-split W into Wt[mat][n][k] bf16.
// Q gets 0.125 * log2(e) folded in (exp2-domain softmax end-to-end).
// ---------------------------------------------------------------------------
__global__ __launch_bounds__(256) void prep_kernel(
    const float* __restrict__ Wq, const float* __restrict__ Wk,
    const float* __restrict__ Wv, ushort* __restrict__ Wth,
    ushort* __restrict__ Wtl) {
  __shared__ float sw[64][65];
  const int mat = blockIdx.x >> 3;
  const int kc  = blockIdx.x & 7;
  const float* W = (mat == 0) ? Wq : ((mat == 1) ? Wk : Wv);
  const float scale = (mat == 0) ? 0.125f * 1.44269504088896f : 1.0f;
  const int tid = threadIdx.x;
#pragma unroll
  for (int j = 0; j < 16; ++j) {
    const int i = tid + 256 * j;                    // 0..4095
    sw[i >> 6][i & 63] =
        W[(size_t)(kc * 64 + (i >> 6)) * 64 + (i & 63)] * scale;
  }
  __syncthreads();
  const int n  = tid >> 2;
  const int ks = (tid & 3) * 16;
  ushort hb[16] __attribute__((aligned(16)));
  ushort lb[16] __attribute__((aligned(16)));
#pragma unroll
  for (int j = 0; j < 16; ++j) {
    const float w = sw[ks + j][n];
    const ushort h = bf16_of(w);
    hb[j] = h;
    lb[j] = bf16_of(w - f_of_bf16(h));
  }
  const size_t base = (size_t)mat * 64 * 512 + (size_t)n * 512 + kc * 64 + ks;
  *reinterpret_cast<short8*>(Wth + base)     = *reinterpret_cast<short8*>(hb);
  *reinterpret_cast<short8*>(Wth + base + 8) = *reinterpret_cast<short8*>(hb + 8);
  *reinterpret_cast<short8*>(Wtl + base)     = *reinterpret_cast<short8*>(lb);
  *reinterpret_cast<short8*>(Wtl + base + 8) = *reinterpret_cast<short8*>(lb + 8);
}

// ---------------------------------------------------------------------------
// Kernel 1 (pgemm v2): R5-proven recipe applied to the projections.
// Block = 16 x-rows staged ONCE in LDS (coalesced); 4 waves each own a
// k-quarter (128) and compute ALL 3 mats from LDS (x reused 3x, W B-frags
// from L2-hot 392 KB Wt); k-quarter partials merged through LDS; wave 0
// does the hi/lo split + stores.  Grid 512 = 2 blocks/CU.
// ---------------------------------------------------------------------------
__global__ __launch_bounds__(256, 2) void pgemm_kernel(
    const float* __restrict__ x, const ushort* __restrict__ Wth,
    const ushort* __restrict__ Wtl,
    ushort* __restrict__ Qh, ushort* __restrict__ Ql,
    ushort* __restrict__ Kh, ushort* __restrict__ Kl,
    ushort* __restrict__ Vt) {
  __shared__ float sx[16][SXP];               // 32.25 KB; reused as merge buf
  float* mb = &sx[0][0];                      // merge buffer alias

  const int tid = threadIdx.x;
  const int wv = tid >> 6, lane = tid & 63;
  const int ln = lane & 15, qd = lane >> 4;
  const int rb = blockIdx.x * 16;

  // stage 16 rows of x: 2048 float4 / 256 threads = 8 each, coalesced
  {
    const float4* xg = reinterpret_cast<const float4*>(x + (size_t)rb * DIN);
#pragma unroll
    for (int j = 0; j < 8; ++j) {
      const int idx = tid + 256 * j;          // float4 index 0..2047
      const int row = idx >> 7;               // 128 float4 per row
      const int col = (idx & 127) * 4;
      *reinterpret_cast<float4*>(&sx[row][col]) = xg[idx];
    }
  }
  __syncthreads();

  f32x4 acc[3][4];
#pragma unroll
  for (int m = 0; m < 3; ++m)
#pragma unroll
    for (int nt = 0; nt < 4; ++nt)
#pragma unroll
      for (int i = 0; i < 4; ++i) acc[m][nt][i] = 0.f;

  const int kb = wv * 128;                    // this wave's k-quarter
  for (int kt = 0; kt < 4; ++kt) {
    const int k0 = kb + kt * 32;
    float xs[8];
    *reinterpret_cast<float4*>(xs) =
        *reinterpret_cast<const float4*>(&sx[ln][k0 + qd * 8]);
    *reinterpret_cast<float4*>(xs + 4) =
        *reinterpret_cast<const float4*>(&sx[ln][k0 + qd * 8 + 4]);
    ushort ah[8] __attribute__((aligned(16)));
    ushort al[8] __attribute__((aligned(16)));
#pragma unroll
    for (int j = 0; j < 8; ++j) {
      const ushort h = bf16_of(xs[j]);
      ah[j] = h;
      al[j] = bf16_of(xs[j] - f_of_bf16(h));
    }
    const short8 Ah = *reinterpret_cast<short8*>(ah);
    const short8 Al = *reinterpret_cast<short8*>(al);
#pragma unroll
    for (int m = 0; m < 3; ++m) {
      const ushort* Wh = Wth + (size_t)m * 64 * 512;
      const ushort* Wl = Wtl + (size_t)m * 64 * 512;
#pragma unroll
      for (int nt = 0; nt < 4; ++nt) {
        const size_t wo = (size_t)(nt * 16 + ln) * 512 + k0 + qd * 8;
        const short8 bh = *reinterpret_cast<const short8*>(Wh + wo);
        const short8 bl = *reinterpret_cast<const short8*>(Wl + wo);
        acc[m][nt] = mfma16(Ah, bh, acc[m][nt]);
        acc[m][nt] = mfma16(Ah, bl, acc[m][nt]);
        acc[m][nt] = mfma16(Al, bh, acc[m][nt]);
      }
    }
  }

  // ---- merge the 4 k-quarter partials through LDS (pairwise tree) ---------
  // phase A: waves 2,3 write; waves 0,1 add.  phase B: wave 1 writes; wave 0 adds.
  const int eidx = (qd * 4) * 64 + ln;        // base of this lane's elements
  __syncthreads();                            // x fully consumed before reuse
  if (wv >= 2) {
    float* b = mb + (size_t)(wv - 2) * 3072;
#pragma unroll
    for (int m = 0; m < 3; ++m)
#pragma unroll
      for (int nt = 0; nt < 4; ++nt)
#pragma unroll
        for (int r = 0; r < 4; ++r)
          b[m * 1024 + eidx + r * 64 + nt * 16] = acc[m][nt][r];
  }
  __syncthreads();
  if (wv < 2) {
    const float* b = mb + (size_t)wv * 3072;
#pragma unroll
    for (int m = 0; m < 3; ++m)
#pragma unroll
      for (int nt = 0; nt < 4; ++nt)
#pragma unroll
        for (int r = 0; r < 4; ++r)
          acc[m][nt][r] += b[m * 1024 + eidx + r * 64 + nt * 16];
  }
  __syncthreads();
  if (wv == 1) {
#pragma unroll
    for (int m = 0; m < 3; ++m)
#pragma unroll
      for (int nt = 0; nt < 4; ++nt)
#pragma unroll
        for (int r = 0; r < 4; ++r)
          mb[m * 1024 + eidx + r * 64 + nt * 16] = acc[m][nt][r];
  }
  __syncthreads();
  if (wv == 0) {
#pragma unroll
    for (int m = 0; m < 3; ++m)
#pragma unroll
      for (int nt = 0; nt < 4; ++nt)
#pragma unroll
        for (int r = 0; r < 4; ++r)
          acc[m][nt][r] += mb[m * 1024 + eidx + r * 64 + nt * 16];

    // Q, K: hi/lo split
#pragma unroll
    for (int m = 0; m < 2; ++m) {
      ushort* H = (m == 0) ? Qh : Kh;
      ushort* L = (m == 0) ? Ql : Kl;
#pragma unroll
      for (int nt = 0; nt < 4; ++nt)
#pragma unroll
        for (int r = 0; r < 4; ++r) {
          const float v = acc[m][nt][r];
          const int row = rb + qd * 4 + r;
          const int col = nt * 16 + ln;
          const ushort h = bf16_of(v);
          H[(size_t)row * DH + col] = h;
          L[(size_t)row * DH + col] = bf16_of(v - f_of_bf16(h));
        }
    }
    // V transposed, packed 8B stores
#pragma unroll
    for (int nt = 0; nt < 4; ++nt) {
      ushort vp[4] __attribute__((aligned(8)));
#pragma unroll
      for (int r = 0; r < 4; ++r) vp[r] = bf16_of(acc[2][nt][r]);
      *reinterpret_cast<us4*>(Vt + (size_t)(nt * 16 + ln) * SEQ + rb + qd * 4) =
          *reinterpret_cast<us4*>(vp);
    }
  }
}

// ---------------------------------------------------------------------------
// Kernel 2 (flash): R5 structure (LDS-staged K/V + register prefetch) with
// the softmax SUM folded into MFMA: a ones-column B-fragment (B[0][k]=1)
// makes accL = P @ 1 accumulate l with alpha-rescaling for free — deletes
// red_sum16 + the serial ps chain (~60 VALU/iter) for +2 MFMA/iter, and
// makes numerator/denominator use identical bf16-quantized P.
// MFMA layouts (measured, m89/m120): C/D col=lane&15, row=(lane>>4)*4+reg;
// A: m=lane&15, k=(lane>>4)*8+j;  B: n=lane&15, k=(lane>>4)*8+j.
// ---------------------------------------------------------------------------
__global__ __launch_bounds__(256, 4) void flash_kernel(
    const ushort* __restrict__ Qh, const ushort* __restrict__ Ql,
    const ushort* __restrict__ Kh, const ushort* __restrict__ Kl,
    const ushort* __restrict__ Vt,
    ushort* __restrict__ Opart, float* __restrict__ Mpart,
    float* __restrict__ Lpart) {
  __shared__ __attribute__((aligned(16))) ushort sKh[BK][LDP];   // 9.2 KB
  __shared__ __attribute__((aligned(16))) ushort sKl[BK][LDP];   // 9.2 KB
  __shared__ __attribute__((aligned(16))) ushort sVt[DH][LDP];   // [vcol][krow]
  __shared__ __attribute__((aligned(16))) ushort sP[4][16][LDP]; // 9.2 KB

  const int tid  = threadIdx.x;
  const int wv   = tid >> 6;
  const int lane = tid & 63;
  const int ln   = lane & 15;
  const int qd   = lane >> 4;
  const int bid  = blockIdx.x;
  const int sg   = bid & 7;
  const int qt   = bid >> 3;        // 0..127 (64-row Q tiles)
  const int qrow0  = qt * 64 + wv * 16;
  const int k0base = sg * CHUNK;

  // staging slices: 512 16B-chunks per tile / 256 threads = 2 each
  const int r0 = tid >> 3,           g0 = (tid & 7) * 8;
  const int r1 = (tid + 256) >> 3,   g1 = (tid & 7) * 8;  // rows 32..63

  // ones-column B-fragment: B[0][k] = 1, B[n!=0][k] = 0
  const ushort one_u = (ln == 0) ? (ushort)0x3F80 : (ushort)0;
  short8 b1;
#pragma unroll
  for (int j = 0; j < 8; ++j) b1[j] = (short)one_u;

  // Q fragments (A-layout), loaded once
  short8 aqh[2], aql[2];
#pragma unroll
  for (int kt = 0; kt < 2; ++kt) {
    aqh[kt] = *reinterpret_cast<const short8*>(
        Qh + (size_t)(qrow0 + ln) * DH + kt * 32 + qd * 8);
    aql[kt] = *reinterpret_cast<const short8*>(
        Ql + (size_t)(qrow0 + ln) * DH + kt * 32 + qd * 8);
  }

  f32x4 accO[4], accL;
  float m_r[4];
#pragma unroll
  for (int nt = 0; nt < 4; ++nt)
#pragma unroll
    for (int i = 0; i < 4; ++i) accO[nt][i] = 0.f;
#pragma unroll
  for (int i = 0; i < 4; ++i) accL[i] = 0.f;
#pragma unroll
  for (int r = 0; r < 4; ++r) m_r[r] = -INFINITY;

  // prefetch registers for one tile-triple
  uint4 pk0, pk1, pl0, pl1, pv0, pv1;
#define LOAD_TILES(k0_)                                                        \
  do {                                                                         \
    pk0 = *reinterpret_cast<const uint4*>(Kh + (size_t)((k0_) + r0) * DH + g0);\
    pk1 = *reinterpret_cast<const uint4*>(Kh + (size_t)((k0_) + r1) * DH + g1);\
    pl0 = *reinterpret_cast<const uint4*>(Kl + (size_t)((k0_) + r0) * DH + g0);\
    pl1 = *reinterpret_cast<const uint4*>(Kl + (size_t)((k0_) + r1) * DH + g1);\
    pv0 = *reinterpret_cast<const uint4*>(Vt + (size_t)r0 * SEQ + (k0_) + g0); \
    pv1 = *reinterpret_cast<const uint4*>(Vt + (size_t)r1 * SEQ + (k0_) + g1); \
  } while (0)

  LOAD_TILES(k0base);

  for (int it = 0; it < NIT; ++it) {
    // drain prefetched tile into LDS (vmcnt wait lands here, one phase old)
    *reinterpret_cast<uint4*>(&sKh[r0][g0]) = pk0;
    *reinterpret_cast<uint4*>(&sKh[r1][g1]) = pk1;
    *reinterpret_cast<uint4*>(&sKl[r0][g0]) = pl0;
    *reinterpret_cast<uint4*>(&sKl[r1][g1]) = pl1;
    *reinterpret_cast<uint4*>(&sVt[r0][g0]) = pv0;
    *reinterpret_cast<uint4*>(&sVt[r1][g1]) = pv1;
    __syncthreads();

    // issue next tile's loads NOW — latency hides under this iter's compute
    const int k0n = k0base + ((it + 1 < NIT) ? (it + 1) : (NIT - 1)) * BK;
    LOAD_TILES(k0n);

    // S tile (16x64): 3-pass split-precision MFMA from LDS
    f32x4 accS[4];
#pragma unroll
    for (int nt = 0; nt < 4; ++nt) {
#pragma unroll
      for (int i = 0; i < 4; ++i) accS[nt][i] = 0.f;
      const short8 bh0 = *reinterpret_cast<const short8*>(&sKh[nt * 16 + ln][qd * 8]);
      const short8 bh1 = *reinterpret_cast<const short8*>(&sKh[nt * 16 + ln][32 + qd * 8]);
      const short8 bl0 = *reinterpret_cast<const short8*>(&sKl[nt * 16 + ln][qd * 8]);
      const short8 bl1 = *reinterpret_cast<const short8*>(&sKl[nt * 16 + ln][32 + qd * 8]);
      accS[nt] = mfma16(aqh[0], bh0, accS[nt]);
      accS[nt] = mfma16(aqh[1], bh1, accS[nt]);
      accS[nt] = mfma16(aqh[0], bl0, accS[nt]);
      accS[nt] = mfma16(aqh[1], bl1, accS[nt]);
      accS[nt] = mfma16(aql[0], bh0, accS[nt]);
      accS[nt] = mfma16(aql[1], bh1, accS[nt]);
    }

    // online softmax, exp2 domain; sum handled by the ones-column MFMA
#pragma unroll
    for (int r = 0; r < 4; ++r) {
      float mx = fmaxf(fmaxf(accS[0][r], accS[1][r]),
                       fmaxf(accS[2][r], accS[3][r]));
      mx = red_max16(mx);
      const float mnew  = fmaxf(m_r[r], mx);
      const float alpha = exp2f(m_r[r] - mnew);
      m_r[r] = mnew;
#pragma unroll
      for (int nt = 0; nt < 4; ++nt) {
        const float p = exp2f(accS[nt][r] - mnew);
        sP[wv][qd * 4 + r][nt * 16 + ln] = bf16_of(p);
        accO[nt][r] *= alpha;
      }
      accL[r] *= alpha;
    }
    // sP is wave-private; DS pipe in-order per wave -> no barrier needed here

    // O += P @ V ; l += P @ 1
#pragma unroll
    for (int kt2 = 0; kt2 < 2; ++kt2) {
      const short8 ap =
          *reinterpret_cast<const short8*>(&sP[wv][ln][kt2 * 32 + qd * 8]);
#pragma unroll
      for (int nt2 = 0; nt2 < 4; ++nt2) {
        const short8 bv = *reinterpret_cast<const short8*>(
            &sVt[nt2 * 16 + ln][kt2 * 32 + qd * 8]);
        accO[nt2] = mfma16(ap, bv, accO[nt2]);
      }
      accL = mfma16(ap, b1, accL);
    }
    __syncthreads();  // all waves done reading this tile before next overwrite
  }
#undef LOAD_TILES

  // partials: un-normalized O (bf16), running m and l (exp2 domain)
  ushort* Ob = Opart + ((size_t)sg * SEQ + qrow0) * DH;
#pragma unroll
  for (int nt = 0; nt < 4; ++nt)
#pragma unroll
    for (int r = 0; r < 4; ++r)
      Ob[(qd * 4 + r) * DH + nt * 16 + ln] = bf16_of(accO[nt][r]);
  if (ln == 0) {   // col 0 of accL holds the row sum
#pragma unroll
    for (int r = 0; r < 4; ++r) {
      Mpart[(size_t)sg * SEQ + qrow0 + qd * 4 + r] = m_r[r];
      Lpart[(size_t)sg * SEQ + qrow0 + qd * 4 + r] = accL[r];
    }
  }
}

// ---------------------------------------------------------------------------
// Kernel 3: merge of the 8 seq-split partials (exp2 domain) + normalize.
// ---------------------------------------------------------------------------
__global__ __launch_bounds__(256) void merge_kernel(
    const ushort* __restrict__ Opart, const float* __restrict__ Mpart,
    const float* __restrict__ Lpart, float* __restrict__ out) {
  const int idx = blockIdx.x * 256 + threadIdx.x;   // 0 .. SEQ*DH
  const int row = idx >> 6;
  const int col = idx & 63;

  float m[SG];
  float M = -INFINITY;
#pragma unroll
  for (int i = 0; i < SG; ++i) {
    m[i] = Mpart[(size_t)i * SEQ + row];
    M = fmaxf(M, m[i]);
  }
  float L = 0.f, acc = 0.f;
#pragma unroll
  for (int i = 0; i < SG; ++i) {
    const float w = exp2f(m[i] - M);
    L   += w * Lpart[(size_t)i * SEQ + row];
    acc += w * f_of_bf16(Opart[((size_t)i * SEQ + row) * DH + col]);
  }
  out[idx] = acc / L;
}

// ---------------------------------------------------------------------------
extern "C" void kernel_launch(void* const* d_in, const int* in_sizes, int n_in,
                              void* d_out, int out_size, void* d_ws, size_t ws_size,
                              hipStream_t stream) {
  const float* x  = (const float*)d_in[0];
  const float* Wq = (const float*)d_in[1];
  const float* Wk = (const float*)d_in[2];
  const float* Wv = (const float*)d_in[3];
  float* out = (float*)d_out;

  // workspace layout — total 14,155,776 B (round-2..5-proven size).
  const size_t S64 = (size_t)SEQ * DH;        // 524288
  ushort* Qh = (ushort*)d_ws;
  ushort* Ql = Qh + S64;
  ushort* Kh = Ql + S64;
  ushort* Kl = Kh + S64;
  ushort* Vt = Kl + S64;
  ushort* Op = Vt + S64;                      // [SG][SEQ][DH] bf16
  ushort* Wth = Op;                           // alias (3*64*512 elems)
  ushort* Wtl = Wth + (size_t)3 * 64 * 512;
  float*  Mp = (float*)(Op + (size_t)SG * S64);
  float*  Lp = Mp + (size_t)SG * SEQ;

  prep_kernel<<<24, 256, 0, stream>>>(Wq, Wk, Wv, Wth, Wtl);
  pgemm_kernel<<<SEQ / 16, 256, 0, stream>>>(x, Wth, Wtl, Qh, Ql, Kh, Kl, Vt);
  flash_kernel<<<(SEQ / 64) * SG, 256, 0, stream>>>(Qh, Ql, Kh, Kl, Vt, Op, Mp, Lp);
  merge_kernel<<<(SEQ * DH) / 256, 256, 0, stream>>>(Op, Mp, Lp, out);
}

// Round 8
// 154.371 us; speedup vs baseline: 1.9901x; 1.0134x over previous
//
#include <hip/hip_runtime.h>
#include <hip/hip_bf16.h>
#include <math.h>

#define SEQ 8192
#define DIN 512
#define DH  64
#define SG  8                 // sequence splits
#define CHUNK (SEQ / SG)      // 1024 K-rows per block
#define BK  64                // K/V rows per iteration
#define NIT (CHUNK / BK)      // 16 iterations
#define LDP 72                // padded LDS row stride (bf16)
#define SXP 516               // padded fp32 x row stride (pgemm)

typedef float f32x4 __attribute__((ext_vector_type(4)));
typedef short short8 __attribute__((ext_vector_type(8)));
typedef ushort us4 __attribute__((ext_vector_type(4)));

static __device__ __forceinline__ ushort bf16_of(float v) {
  __hip_bfloat16 h = __float2bfloat16(v);
  return *reinterpret_cast<ushort*>(&h);
}
static __device__ __forceinline__ float f_of_bf16(ushort u) {
  __hip_bfloat16 h;
  *reinterpret_cast<ushort*>(&h) = u;
  return __bfloat162float(h);
}
static __device__ __forceinline__ f32x4 mfma16(short8 a, short8 b, f32x4 c) {
  return __builtin_amdgcn_mfma_f32_16x16x32_bf16(a, b, c, 0, 0, 0);
}
// packed bf16x2 (low = a, high = b) — v_cvt_pk_bf16_f32 path
static __device__ __forceinline__ uint pack_bf16(float a, float b) {
  __hip_bfloat162 h2 = __float22bfloat162_rn(make_float2(a, b));
  return *reinterpret_cast<uint*>(&h2);
}

// ---------------------------------------------------------------------------
// Kernel 0 (prep): transpose + hi/lo-split W into Wt[mat][n][k] bf16.
// Q gets 0.125 * log2(e) folded in (exp2-domain softmax end-to-end).
// ---------------------------------------------------------------------------
__global__ __launch_bounds__(256) void prep_kernel(
    const float* __restrict__ Wq, const float* __restrict__ Wk,
    const float* __restrict__ Wv, ushort* __restrict__ Wth,
    ushort* __restrict__ Wtl) {
  __shared__ float sw[64][65];
  const int mat = blockIdx.x >> 3;
  const int kc  = blockIdx.x & 7;
  const float* W = (mat == 0) ? Wq : ((mat == 1) ? Wk : Wv);
  const float scale = (mat == 0) ? 0.125f * 1.44269504088896f : 1.0f;
  const int tid = threadIdx.x;
#pragma unroll
  for (int j = 0; j < 16; ++j) {
    const int i = tid + 256 * j;                    // 0..4095
    sw[i >> 6][i & 63] =
        W[(size_t)(kc * 64 + (i >> 6)) * 64 + (i & 63)] * scale;
  }
  __syncthreads();
  const int n  = tid >> 2;
  const int ks = (tid & 3) * 16;
  ushort hb[16] __attribute__((aligned(16)));
  ushort lb[16] __attribute__((aligned(16)));
#pragma unroll
  for (int j = 0; j < 16; ++j) {
    const float w = sw[ks + j][n];
    const ushort h = bf16_of(w);
    hb[j] = h;
    lb[j] = bf16_of(w - f_of_bf16(h));
  }
  const size_t base = (size_t)mat * 64 * 512 + (size_t)n * 512 + kc * 64 + ks;
  *reinterpret_cast<short8*>(Wth + base)     = *reinterpret_cast<short8*>(hb);
  *reinterpret_cast<short8*>(Wth + base + 8) = *reinterpret_cast<short8*>(hb + 8);
  *reinterpret_cast<short8*>(Wtl + base)     = *reinterpret_cast<short8*>(lb);
  *reinterpret_cast<short8*>(Wtl + base + 8) = *reinterpret_cast<short8*>(lb + 8);
}

// ---------------------------------------------------------------------------
// Kernel 1 (pgemm): unchanged from R6 (control variable).
// ---------------------------------------------------------------------------
__global__ __launch_bounds__(256, 2) void pgemm_kernel(
    const float* __restrict__ x, const ushort* __restrict__ Wth,
    const ushort* __restrict__ Wtl,
    ushort* __restrict__ Qh, ushort* __restrict__ Ql,
    ushort* __restrict__ Kh, ushort* __restrict__ Kl,
    ushort* __restrict__ Vt) {
  __shared__ float sx[16][SXP];               // 32.25 KB; reused as merge buf
  float* mb = &sx[0][0];

  const int tid = threadIdx.x;
  const int wv = tid >> 6, lane = tid & 63;
  const int ln = lane & 15, qd = lane >> 4;
  const int rb = blockIdx.x * 16;

  {
    const float4* xg = reinterpret_cast<const float4*>(x + (size_t)rb * DIN);
#pragma unroll
    for (int j = 0; j < 8; ++j) {
      const int idx = tid + 256 * j;
      const int row = idx >> 7;
      const int col = (idx & 127) * 4;
      *reinterpret_cast<float4*>(&sx[row][col]) = xg[idx];
    }
  }
  __syncthreads();

  f32x4 acc[3][4];
#pragma unroll
  for (int m = 0; m < 3; ++m)
#pragma unroll
    for (int nt = 0; nt < 4; ++nt)
#pragma unroll
      for (int i = 0; i < 4; ++i) acc[m][nt][i] = 0.f;

  const int kb = wv * 128;
  for (int kt = 0; kt < 4; ++kt) {
    const int k0 = kb + kt * 32;
    float xs[8];
    *reinterpret_cast<float4*>(xs) =
        *reinterpret_cast<const float4*>(&sx[ln][k0 + qd * 8]);
    *reinterpret_cast<float4*>(xs + 4) =
        *reinterpret_cast<const float4*>(&sx[ln][k0 + qd * 8 + 4]);
    ushort ah[8] __attribute__((aligned(16)));
    ushort al[8] __attribute__((aligned(16)));
#pragma unroll
    for (int j = 0; j < 8; ++j) {
      const ushort h = bf16_of(xs[j]);
      ah[j] = h;
      al[j] = bf16_of(xs[j] - f_of_bf16(h));
    }
    const short8 Ah = *reinterpret_cast<short8*>(ah);
    const short8 Al = *reinterpret_cast<short8*>(al);
#pragma unroll
    for (int m = 0; m < 3; ++m) {
      const ushort* Wh = Wth + (size_t)m * 64 * 512;
      const ushort* Wl = Wtl + (size_t)m * 64 * 512;
#pragma unroll
      for (int nt = 0; nt < 4; ++nt) {
        const size_t wo = (size_t)(nt * 16 + ln) * 512 + k0 + qd * 8;
        const short8 bh = *reinterpret_cast<const short8*>(Wh + wo);
        const short8 bl = *reinterpret_cast<const short8*>(Wl + wo);
        acc[m][nt] = mfma16(Ah, bh, acc[m][nt]);
        acc[m][nt] = mfma16(Ah, bl, acc[m][nt]);
        acc[m][nt] = mfma16(Al, bh, acc[m][nt]);
      }
    }
  }

  const int eidx = (qd * 4) * 64 + ln;
  __syncthreads();
  if (wv >= 2) {
    float* b = mb + (size_t)(wv - 2) * 3072;
#pragma unroll
    for (int m = 0; m < 3; ++m)
#pragma unroll
      for (int nt = 0; nt < 4; ++nt)
#pragma unroll
        for (int r = 0; r < 4; ++r)
          b[m * 1024 + eidx + r * 64 + nt * 16] = acc[m][nt][r];
  }
  __syncthreads();
  if (wv < 2) {
    const float* b = mb + (size_t)wv * 3072;
#pragma unroll
    for (int m = 0; m < 3; ++m)
#pragma unroll
      for (int nt = 0; nt < 4; ++nt)
#pragma unroll
        for (int r = 0; r < 4; ++r)
          acc[m][nt][r] += b[m * 1024 + eidx + r * 64 + nt * 16];
  }
  __syncthreads();
  if (wv == 1) {
#pragma unroll
    for (int m = 0; m < 3; ++m)
#pragma unroll
      for (int nt = 0; nt < 4; ++nt)
#pragma unroll
        for (int r = 0; r < 4; ++r)
          mb[m * 1024 + eidx + r * 64 + nt * 16] = acc[m][nt][r];
  }
  __syncthreads();
  if (wv == 0) {
#pragma unroll
    for (int m = 0; m < 3; ++m)
#pragma unroll
      for (int nt = 0; nt < 4; ++nt)
#pragma unroll
        for (int r = 0; r < 4; ++r)
          acc[m][nt][r] += mb[m * 1024 + eidx + r * 64 + nt * 16];

#pragma unroll
    for (int m = 0; m < 2; ++m) {
      ushort* H = (m == 0) ? Qh : Kh;
      ushort* L = (m == 0) ? Ql : Kl;
#pragma unroll
      for (int nt = 0; nt < 4; ++nt)
#pragma unroll
        for (int r = 0; r < 4; ++r) {
          const float v = acc[m][nt][r];
          const int row = rb + qd * 4 + r;
          const int col = nt * 16 + ln;
          const ushort h = bf16_of(v);
          H[(size_t)row * DH + col] = h;
          L[(size_t)row * DH + col] = bf16_of(v - f_of_bf16(h));
        }
    }
#pragma unroll
    for (int nt = 0; nt < 4; ++nt) {
      ushort vp[4] __attribute__((aligned(8)));
#pragma unroll
      for (int r = 0; r < 4; ++r) vp[r] = bf16_of(acc[2][nt][r]);
      *reinterpret_cast<us4*>(Vt + (size_t)(nt * 16 + ln) * SEQ + rb + qd * 4) =
          *reinterpret_cast<us4*>(vp);
    }
  }
}

// ---------------------------------------------------------------------------
// Kernel 2 (flash v3 FIXED): transposed score tile S^T = K·Q^T.
// R7 bug: the P^T gather selected pkd[ntA] vs pkd[ntB] at the SOURCE lane
// (shfl fetches the source's value of the expression), but the nt choice
// depends on the DESTINATION's qd (nt_src = kt2*2 + qd_dest>>1, while the
// source lane's own selector evaluates to qd_dest&1) — each source dword is
// demanded by two dests needing different nt.  Fix: shfl BOTH candidates and
// cndmask at the destination (2 shfl + 1 select per dword slot).
// Mapping (re-derived): dest (qd,j) needs P^T[k=kt2*32+qd*8+j][q=ln] =
// pkd[kt2*2+(qd>>1)][(j&3)>>1] from lane ((qd&1)*2+(j>>2))*16+ln.
// ---------------------------------------------------------------------------
__global__ __launch_bounds__(256, 4) void flash_kernel(
    const ushort* __restrict__ Qh, const ushort* __restrict__ Ql,
    const ushort* __restrict__ Kh, const ushort* __restrict__ Kl,
    const ushort* __restrict__ Vt,
    ushort* __restrict__ Opart, float* __restrict__ Mpart,
    float* __restrict__ Lpart) {
  __shared__ __attribute__((aligned(16))) ushort sKh[BK][LDP];   // 9.2 KB
  __shared__ __attribute__((aligned(16))) ushort sKl[BK][LDP];   // 9.2 KB
  __shared__ __attribute__((aligned(16))) ushort sVt[DH][LDP];   // 9.2 KB

  const int tid  = threadIdx.x;
  const int wv   = tid >> 6;
  const int lane = tid & 63;
  const int ln   = lane & 15;
  const int qd   = lane >> 4;
  const int bid  = blockIdx.x;
  const int sg   = bid & 7;
  const int qt   = bid >> 3;        // 0..127 (64-row Q tiles)
  const int qrow0  = qt * 64 + wv * 16;
  const int k0base = sg * CHUNK;

  // staging slices: 512 16B-chunks per tile / 256 threads = 2 each
  const int r0 = tid >> 3, g0 = (tid & 7) * 8;
  const int r1 = r0 + 32,  g1 = g0;

  // gather source lanes for the P^T fragment
  const int sA = ((qd & 1) * 2) * 16 + ln;   // j>>2 == 0
  const int sB = sA + 16;                    // j>>2 == 1
  const bool hiQd = (qd >= 2);

  // ones A-fragment: A[0][k] = 1 (lanes with ln==0), else 0
  const ushort one_u = (ln == 0) ? (ushort)0x3F80 : (ushort)0;
  short8 afr1;
#pragma unroll
  for (int j = 0; j < 8; ++j) afr1[j] = (short)one_u;

  // Q fragments (B-operand), loaded once
  short8 bqh[2], bql[2];
#pragma unroll
  for (int kt = 0; kt < 2; ++kt) {
    bqh[kt] = *reinterpret_cast<const short8*>(
        Qh + (size_t)(qrow0 + ln) * DH + kt * 32 + qd * 8);
    bql[kt] = *reinterpret_cast<const short8*>(
        Ql + (size_t)(qrow0 + ln) * DH + kt * 32 + qd * 8);
  }

  f32x4 accO[4], accL;
  float m_run = -INFINITY;
#pragma unroll
  for (int nt = 0; nt < 4; ++nt)
#pragma unroll
    for (int i = 0; i < 4; ++i) accO[nt][i] = 0.f;
#pragma unroll
  for (int i = 0; i < 4; ++i) accL[i] = 0.f;

  uint4 pk0, pk1, pl0, pl1, pv0, pv1;
#define LOAD_TILES(k0_)                                                        \
  do {                                                                         \
    pk0 = *reinterpret_cast<const uint4*>(Kh + (size_t)((k0_) + r0) * DH + g0);\
    pk1 = *reinterpret_cast<const uint4*>(Kh + (size_t)((k0_) + r1) * DH + g1);\
    pl0 = *reinterpret_cast<const uint4*>(Kl + (size_t)((k0_) + r0) * DH + g0);\
    pl1 = *reinterpret_cast<const uint4*>(Kl + (size_t)((k0_) + r1) * DH + g1);\
    pv0 = *reinterpret_cast<const uint4*>(Vt + (size_t)r0 * SEQ + (k0_) + g0); \
    pv1 = *reinterpret_cast<const uint4*>(Vt + (size_t)r1 * SEQ + (k0_) + g1); \
  } while (0)

  LOAD_TILES(k0base);

  for (int it = 0; it < NIT; ++it) {
    *reinterpret_cast<uint4*>(&sKh[r0][g0]) = pk0;
    *reinterpret_cast<uint4*>(&sKh[r1][g1]) = pk1;
    *reinterpret_cast<uint4*>(&sKl[r0][g0]) = pl0;
    *reinterpret_cast<uint4*>(&sKl[r1][g1]) = pl1;
    *reinterpret_cast<uint4*>(&sVt[r0][g0]) = pv0;
    *reinterpret_cast<uint4*>(&sVt[r1][g1]) = pv1;
    __syncthreads();

    const int k0n = k0base + ((it + 1 < NIT) ? (it + 1) : (NIT - 1)) * BK;
    LOAD_TILES(k0n);

    // S^T tile (64x16): A = K rows (LDS), B = Q (regs).  3-pass split.
    f32x4 accS[4];
#pragma unroll
    for (int nt = 0; nt < 4; ++nt) {
#pragma unroll
      for (int i = 0; i < 4; ++i) accS[nt][i] = 0.f;
      const short8 kh0 = *reinterpret_cast<const short8*>(&sKh[nt * 16 + ln][qd * 8]);
      const short8 kh1 = *reinterpret_cast<const short8*>(&sKh[nt * 16 + ln][32 + qd * 8]);
      const short8 kl0 = *reinterpret_cast<const short8*>(&sKl[nt * 16 + ln][qd * 8]);
      const short8 kl1 = *reinterpret_cast<const short8*>(&sKl[nt * 16 + ln][32 + qd * 8]);
      accS[nt] = mfma16(kh0, bqh[0], accS[nt]);   // Khi * Qhi
      accS[nt] = mfma16(kh1, bqh[1], accS[nt]);
      accS[nt] = mfma16(kh0, bql[0], accS[nt]);   // Khi * Qlo
      accS[nt] = mfma16(kh1, bql[1], accS[nt]);
      accS[nt] = mfma16(kl0, bqh[0], accS[nt]);   // Klo * Qhi
      accS[nt] = mfma16(kl1, bqh[1], accS[nt]);
    }

    // per-lane online softmax (lane owns q-row = ln), exp2 domain
    float tmax = fmaxf(fmaxf(fmaxf(accS[0][0], accS[0][1]), fmaxf(accS[0][2], accS[0][3])),
                       fmaxf(fmaxf(accS[1][0], accS[1][1]), fmaxf(accS[1][2], accS[1][3])));
    tmax = fmaxf(tmax,
                 fmaxf(fmaxf(fmaxf(accS[2][0], accS[2][1]), fmaxf(accS[2][2], accS[2][3])),
                       fmaxf(fmaxf(accS[3][0], accS[3][1]), fmaxf(accS[3][2], accS[3][3]))));
    tmax = fmaxf(tmax, __shfl_xor(tmax, 16));
    tmax = fmaxf(tmax, __shfl_xor(tmax, 32));
    const float mnew  = fmaxf(m_run, tmax);
    const float alpha = exp2f(m_run - mnew);
    m_run = mnew;

    uint pkd[4][2];
#pragma unroll
    for (int nt = 0; nt < 4; ++nt) {
      const float p0 = exp2f(accS[nt][0] - mnew);
      const float p1 = exp2f(accS[nt][1] - mnew);
      const float p2 = exp2f(accS[nt][2] - mnew);
      const float p3 = exp2f(accS[nt][3] - mnew);
      pkd[nt][0] = pack_bf16(p0, p1);
      pkd[nt][1] = pack_bf16(p2, p3);
#pragma unroll
      for (int i = 0; i < 4; ++i) accO[nt][i] *= alpha;
    }
    accL[0] *= alpha;

    // O^T += V^T · P^T ; l += 1~ · P^T
    // FIXED gather: fetch both nt candidates, select at destination.
#pragma unroll
    for (int kt2 = 0; kt2 < 2; ++kt2) {
      const uint pA0 = pkd[kt2 * 2][0],     pA1 = pkd[kt2 * 2][1];
      const uint pB0 = pkd[kt2 * 2 + 1][0], pB1 = pkd[kt2 * 2 + 1][1];
      uint4 du;
      {
        const uint xA = (uint)__shfl((int)pA0, sA);
        const uint xB = (uint)__shfl((int)pB0, sA);
        du.x = hiQd ? xB : xA;
        const uint yA = (uint)__shfl((int)pA1, sA);
        const uint yB = (uint)__shfl((int)pB1, sA);
        du.y = hiQd ? yB : yA;
        const uint zA = (uint)__shfl((int)pA0, sB);
        const uint zB = (uint)__shfl((int)pB0, sB);
        du.z = hiQd ? zB : zA;
        const uint wA = (uint)__shfl((int)pA1, sB);
        const uint wB = (uint)__shfl((int)pB1, sB);
        du.w = hiQd ? wB : wA;
      }
      const short8 pfrag = *reinterpret_cast<short8*>(&du);
#pragma unroll
      for (int nt2 = 0; nt2 < 4; ++nt2) {
        const short8 vA = *reinterpret_cast<const short8*>(
            &sVt[nt2 * 16 + ln][kt2 * 32 + qd * 8]);
        accO[nt2] = mfma16(vA, pfrag, accO[nt2]);
      }
      accL = mfma16(afr1, pfrag, accL);
    }
    __syncthreads();  // all waves done with this tile before next overwrite
  }
#undef LOAD_TILES

  // epilogue: lane holds q-row = qrow0+ln, vcols nt*16+qd*4+(0..3)
  const int qrow = qrow0 + ln;
  ushort* Ob = Opart + ((size_t)sg * SEQ + qrow) * DH;
#pragma unroll
  for (int nt = 0; nt < 4; ++nt) {
    ushort op[4] __attribute__((aligned(8)));
#pragma unroll
    for (int r = 0; r < 4; ++r) op[r] = bf16_of(accO[nt][r]);
    *reinterpret_cast<us4*>(Ob + nt * 16 + qd * 4) =
        *reinterpret_cast<us4*>(op);
  }
  if (qd == 0) {
    Mpart[(size_t)sg * SEQ + qrow] = m_run;
    Lpart[(size_t)sg * SEQ + qrow] = accL[0];
  }
}

// ---------------------------------------------------------------------------
// Kernel 3: merge of the 8 seq-split partials (exp2 domain), vectorized x4.
// ---------------------------------------------------------------------------
__global__ __launch_bounds__(256) void merge_kernel(
    const ushort* __restrict__ Opart, const float* __restrict__ Mpart,
    const float* __restrict__ Lpart, float* __restrict__ out) {
  const int idx = blockIdx.x * 256 + threadIdx.x;   // 0 .. SEQ*16
  const int row = idx >> 4;
  const int c4  = (idx & 15) * 4;

  float m[SG];
  float M = -INFINITY;
#pragma unroll
  for (int i = 0; i < SG; ++i) {
    m[i] = Mpart[(size_t)i * SEQ + row];
    M = fmaxf(M, m[i]);
  }
  float L = 0.f;
  float a0 = 0.f, a1 = 0.f, a2 = 0.f, a3 = 0.f;
#pragma unroll
  for (int i = 0; i < SG; ++i) {
    const float w = exp2f(m[i] - M);
    L += w * Lpart[(size_t)i * SEQ + row];
    const us4 o = *reinterpret_cast<const us4*>(
        Opart + ((size_t)i * SEQ + row) * DH + c4);
    a0 += w * f_of_bf16(o[0]);
    a1 += w * f_of_bf16(o[1]);
    a2 += w * f_of_bf16(o[2]);
    a3 += w * f_of_bf16(o[3]);
  }
  const float rL = 1.0f / L;
  float4 res = make_float4(a0 * rL, a1 * rL, a2 * rL, a3 * rL);
  *reinterpret_cast<float4*>(out + (size_t)row * DH + c4) = res;
}

// ---------------------------------------------------------------------------
extern "C" void kernel_launch(void* const* d_in, const int* in_sizes, int n_in,
                              void* d_out, int out_size, void* d_ws, size_t ws_size,
                              hipStream_t stream) {
  const float* x  = (const float*)d_in[0];
  const float* Wq = (const float*)d_in[1];
  const float* Wk = (const float*)d_in[2];
  const float* Wv = (const float*)d_in[3];
  float* out = (float*)d_out;

  // workspace layout — total 14,155,776 B (round-2..6-proven size).
  const size_t S64 = (size_t)SEQ * DH;        // 524288
  ushort* Qh = (ushort*)d_ws;
  ushort* Ql = Qh + S64;
  ushort* Kh = Ql + S64;
  ushort* Kl = Kh + S64;
  ushort* Vt = Kl + S64;
  ushort* Op = Vt + S64;                      // [SG][SEQ][DH] bf16
  ushort* Wth = Op;                           // alias (3*64*512 elems)
  ushort* Wtl = Wth + (size_t)3 * 64 * 512;
  float*  Mp = (float*)(Op + (size_t)SG * S64);
  float*  Lp = Mp + (size_t)SG * SEQ;

  prep_kernel<<<24, 256, 0, stream>>>(Wq, Wk, Wv, Wth, Wtl);
  pgemm_kernel<<<SEQ / 16, 256, 0, stream>>>(x, Wth, Wtl, Qh, Ql, Kh, Kl, Vt);
  flash_kernel<<<(SEQ / 64) * SG, 256, 0, stream>>>(Qh, Ql, Kh, Kl, Vt, Op, Mp, Lp);
  merge_kernel<<<(SEQ * 16) / 256, 256, 0, stream>>>(Op, Mp, Lp, out);
}